// Round 1
// baseline (1589.319 us; speedup 1.0000x reference)
//
#include <hip/hip_runtime.h>
#include <math.h>

#define HID 1024
#define NH 16
#define DH 64
#define BATCH 8
#define SEQ 1024

// ---------------------------------------------------------------------------
// GEMM: Y[M,N] = X[M,K] @ W[N,K]^T (+ bias[n])
// BM=BN=128, BK=16, 256 threads, 8x8 micro-tile per thread. f32 VALU.
// ---------------------------------------------------------------------------
__global__ __launch_bounds__(256)
void gemm_xwt_f32(const float* __restrict__ X, const float* __restrict__ W,
                  const float* __restrict__ bias, float* __restrict__ Y,
                  int M, int N, int K)
{
    __shared__ float As[16][128];   // As[k][m]  = X[m0+m][kb+k]
    __shared__ float Bs[16][128];   // Bs[k][n]  = W[n0+n][kb+k]

    const int t  = threadIdx.x;
    const int tx = t & 15;          // 0..15 -> 8 output cols each
    const int ty = t >> 4;          // 0..15 -> 8 output rows each
    const int m0 = blockIdx.y * 128;
    const int n0 = blockIdx.x * 128;

    float acc[8][8];
#pragma unroll
    for (int i = 0; i < 8; ++i)
#pragma unroll
        for (int j = 0; j < 8; ++j) acc[i][j] = 0.f;

    for (int kb = 0; kb < K; kb += 16) {
        // stage tiles: 128 rows x 16 k each = 512 float4 per tile, 2 per thread
#pragma unroll
        for (int it = 0; it < 2; ++it) {
            int id  = t + it * 256;   // float4 id within tile
            int row = id >> 2;        // 4 float4 per row (16 floats)
            int kq  = id & 3;
            float4 va = *(const float4*)&X[(size_t)(m0 + row) * K + kb + kq * 4];
            As[kq*4+0][row] = va.x;
            As[kq*4+1][row] = va.y;
            As[kq*4+2][row] = va.z;
            As[kq*4+3][row] = va.w;
            float4 vb = *(const float4*)&W[(size_t)(n0 + row) * K + kb + kq * 4];
            Bs[kq*4+0][row] = vb.x;
            Bs[kq*4+1][row] = vb.y;
            Bs[kq*4+2][row] = vb.z;
            Bs[kq*4+3][row] = vb.w;
        }
        __syncthreads();

#pragma unroll
        for (int k = 0; k < 16; ++k) {
            float4 a0 = *(const float4*)&As[k][ty*8];
            float4 a1 = *(const float4*)&As[k][ty*8+4];
            float4 b0 = *(const float4*)&Bs[k][tx*8];
            float4 b1 = *(const float4*)&Bs[k][tx*8+4];
            float a[8] = {a0.x,a0.y,a0.z,a0.w,a1.x,a1.y,a1.z,a1.w};
            float b[8] = {b0.x,b0.y,b0.z,b0.w,b1.x,b1.y,b1.z,b1.w};
#pragma unroll
            for (int i = 0; i < 8; ++i)
#pragma unroll
                for (int j = 0; j < 8; ++j)
                    acc[i][j] = fmaf(a[i], b[j], acc[i][j]);
        }
        __syncthreads();
    }

#pragma unroll
    for (int i = 0; i < 8; ++i) {
        int m = m0 + ty*8 + i;
#pragma unroll
        for (int j = 0; j < 8; j += 4) {
            int n = n0 + tx*8 + j;
            float4 o;
            o.x = acc[i][j+0]; o.y = acc[i][j+1];
            o.z = acc[i][j+2]; o.w = acc[i][j+3];
            if (bias) {
                o.x += bias[n+0]; o.y += bias[n+1];
                o.z += bias[n+2]; o.w += bias[n+3];
            }
            *(float4*)&Y[(size_t)m * N + n] = o;
        }
    }
}

// ---------------------------------------------------------------------------
// Flash-style attention, f32. One block = (b, head, 64 Q rows).
// Streams K/V in 64-wide chunks; online softmax with per-row (m,l).
// Thread (tx,ty): score rows ty*4..+3, score cols / head-dims tx*4..+3.
// ---------------------------------------------------------------------------
__global__ __launch_bounds__(256)
void attn_f32(const float* __restrict__ Qg, const float* __restrict__ Kg,
              const float* __restrict__ Vg, float* __restrict__ Hd)
{
    __shared__ float Qt[64][68];   // [d][row]  (transposed Q tile)
    __shared__ float Kt[64][68];   // [d][col]  (transposed K chunk)
    __shared__ float Vs[64][68];   // [k][d]
    __shared__ float Pt[64][68];   // [k][row]  (transposed probabilities)

    const int t  = threadIdx.x;
    const int tx = t & 15;
    const int ty = t >> 4;
    const int q0 = blockIdx.x * 64;
    const int n  = blockIdx.y;
    const int b  = blockIdx.z;

    // load Q tile transposed: 64 rows x 64 d = 1024 float4, 4 per thread
#pragma unroll
    for (int it = 0; it < 4; ++it) {
        int id  = t + it * 256;
        int row = id >> 4;        // 16 float4 per row
        int d4  = id & 15;
        float4 v = *(const float4*)&Qg[((size_t)(b*SEQ + q0 + row)) * HID + n*DH + d4*4];
        Qt[d4*4+0][row] = v.x;
        Qt[d4*4+1][row] = v.y;
        Qt[d4*4+2][row] = v.z;
        Qt[d4*4+3][row] = v.w;
    }

    float m_i[4], l_i[4], acc[4][4];
#pragma unroll
    for (int i = 0; i < 4; ++i) {
        m_i[i] = -INFINITY; l_i[i] = 0.f;
#pragma unroll
        for (int j = 0; j < 4; ++j) acc[i][j] = 0.f;
    }

    for (int kc = 0; kc < SEQ/64; ++kc) {
        __syncthreads();   // previous chunk's reads of Kt/Vs/Pt are done
        // stage K (transposed) and V (natural) chunks
#pragma unroll
        for (int it = 0; it < 4; ++it) {
            int id  = t + it * 256;
            int row = id >> 4;
            int d4  = id & 15;
            size_t g = ((size_t)(b*SEQ + kc*64 + row)) * HID + n*DH + d4*4;
            float4 kv = *(const float4*)&Kg[g];
            Kt[d4*4+0][row] = kv.x;
            Kt[d4*4+1][row] = kv.y;
            Kt[d4*4+2][row] = kv.z;
            Kt[d4*4+3][row] = kv.w;
            float4 vv = *(const float4*)&Vg[g];
            *(float4*)&Vs[row][d4*4] = vv;
        }
        __syncthreads();

        // scores: s[i][j] = sum_d Q[ty*4+i][d] * K[tx*4+j][d]
        float s[4][4] = {{0.f}};
#pragma unroll 16
        for (int d = 0; d < 64; ++d) {
            float4 q4 = *(const float4*)&Qt[d][ty*4];
            float4 k4 = *(const float4*)&Kt[d][tx*4];
            float qa[4] = {q4.x, q4.y, q4.z, q4.w};
            float kb4[4] = {k4.x, k4.y, k4.z, k4.w};
#pragma unroll
            for (int i = 0; i < 4; ++i)
#pragma unroll
                for (int j = 0; j < 4; ++j)
                    s[i][j] = fmaf(qa[i], kb4[j], s[i][j]);
        }

        // online softmax per row (16 tx lanes share a row; lanes are contiguous)
#pragma unroll
        for (int i = 0; i < 4; ++i) {
#pragma unroll
            for (int j = 0; j < 4; ++j) s[i][j] *= 0.125f;   // 1/sqrt(64)
            float rm = fmaxf(fmaxf(s[i][0], s[i][1]), fmaxf(s[i][2], s[i][3]));
            rm = fmaxf(rm, __shfl_xor(rm, 1));
            rm = fmaxf(rm, __shfl_xor(rm, 2));
            rm = fmaxf(rm, __shfl_xor(rm, 4));
            rm = fmaxf(rm, __shfl_xor(rm, 8));
            float mnew = fmaxf(m_i[i], rm);
            float scl  = expf(m_i[i] - mnew);   // first chunk: exp(-inf)=0
            float p[4], rs = 0.f;
#pragma unroll
            for (int j = 0; j < 4; ++j) { p[j] = expf(s[i][j] - mnew); rs += p[j]; }
            rs += __shfl_xor(rs, 1);
            rs += __shfl_xor(rs, 2);
            rs += __shfl_xor(rs, 4);
            rs += __shfl_xor(rs, 8);
            l_i[i] = l_i[i] * scl + rs;
            m_i[i] = mnew;
#pragma unroll
            for (int j = 0; j < 4; ++j) acc[i][j] *= scl;
#pragma unroll
            for (int j = 0; j < 4; ++j) Pt[tx*4+j][ty*4+i] = p[j];
        }
        __syncthreads();

        // acc[i][j] += sum_k P[ty*4+i][k] * V[k][tx*4+j]
#pragma unroll 8
        for (int k = 0; k < 64; ++k) {
            float4 p4 = *(const float4*)&Pt[k][ty*4];
            float4 v4 = *(const float4*)&Vs[k][tx*4];
            float pa[4] = {p4.x, p4.y, p4.z, p4.w};
            float vb4[4] = {v4.x, v4.y, v4.z, v4.w};
#pragma unroll
            for (int i = 0; i < 4; ++i)
#pragma unroll
                for (int j = 0; j < 4; ++j)
                    acc[i][j] = fmaf(pa[i], vb4[j], acc[i][j]);
        }
    }

    // normalize and write heads in concat layout [b, q, n*64+d]
#pragma unroll
    for (int i = 0; i < 4; ++i) {
        float inv = 1.f / l_i[i];
        float4 o;
        o.x = acc[i][0]*inv; o.y = acc[i][1]*inv;
        o.z = acc[i][2]*inv; o.w = acc[i][3]*inv;
        *(float4*)&Hd[((size_t)(b*SEQ + q0 + ty*4 + i)) * HID + n*DH + tx*4] = o;
    }
}

// ---------------------------------------------------------------------------
extern "C" void kernel_launch(void* const* d_in, const int* in_sizes, int n_in,
                              void* d_out, int out_size, void* d_ws, size_t ws_size,
                              hipStream_t stream)
{
    const float* dec = (const float*)d_in[0];   // [8,1024,1024]
    const float* enc = (const float*)d_in[1];   // [8,1024,1024]
    const float* Wq  = (const float*)d_in[2];   // [16,64,1024] == [1024,1024]
    const float* Wk  = (const float*)d_in[3];
    const float* Wv  = (const float*)d_in[4];
    const float* Wo  = (const float*)d_in[5];   // [1024,1024]
    const float* bo  = (const float*)d_in[6];   // [1024]
    float* out = (float*)d_out;

    const size_t TOK = (size_t)BATCH * SEQ * HID;   // 8M floats = 32 MiB
    float* Qb = (float*)d_ws;
    float* Kb = Qb + TOK;
    float* Vb = Kb + TOK;
    float* Cc = Vb + TOK;   // concat heads; total ws use = 128 MiB

    const int M = BATCH * SEQ;   // 8192
    dim3 gg(HID/128, M/128);     // (8, 64)

    gemm_xwt_f32<<<gg, 256, 0, stream>>>(dec, Wq, nullptr, Qb, M, HID, HID);
    gemm_xwt_f32<<<gg, 256, 0, stream>>>(enc, Wk, nullptr, Kb, M, HID, HID);
    gemm_xwt_f32<<<gg, 256, 0, stream>>>(enc, Wv, nullptr, Vb, M, HID, HID);

    attn_f32<<<dim3(SEQ/64, NH, BATCH), 256, 0, stream>>>(Qb, Kb, Vb, Cc);

    gemm_xwt_f32<<<gg, 256, 0, stream>>>(Cc, Wo, bo, out, M, HID, HID);
}

// Round 2
// 488.650 us; speedup vs baseline: 3.2525x; 3.2525x over previous
//
#include <hip/hip_runtime.h>
#include <math.h>

#define HID 1024
#define NH 16
#define DH 64
#define BATCH 8
#define SEQ 1024
#define MTOT (BATCH * SEQ) /* 8192 */

typedef __attribute__((ext_vector_type(8))) short bfrag;           // 8 bf16 (4 VGPR) MFMA operand
typedef __attribute__((ext_vector_type(4))) float f32x4;           // MFMA accumulator
typedef __attribute__((ext_vector_type(8))) unsigned short us8;
typedef __attribute__((ext_vector_type(4))) unsigned short us4;
typedef unsigned int u32;
typedef unsigned short u16;

__device__ __forceinline__ u16 f2b(float f) {              // f32 -> bf16 RNE
    u32 u = __float_as_uint(f);
    return (u16)((u + 0x7FFFu + ((u >> 16) & 1u)) >> 16);
}
__device__ __forceinline__ float b2f(u16 h) { return __uint_as_float(((u32)h) << 16); }

__device__ __forceinline__ void gl_lds16(const void* g, void* l) {
    __builtin_amdgcn_global_load_lds(
        (const __attribute__((address_space(1))) unsigned int*)g,
        (__attribute__((address_space(3))) unsigned int*)l, 16, 0, 0);
}

// XOR swizzle on byte addr within an 8KB tile of 64B logical rows (kills the
// stride-64B 8-way read conflict; verified 2-way max per quarter-wave).
__device__ __forceinline__ u32 swz(u32 L) { return L ^ (((L >> 6) & 7u) << 4); }
// inverse (for pre-swizzling the global source of global_load_lds)
__device__ __forceinline__ u32 unswz(u32 p) {
    u32 b = ((((p >> 6) ^ (p >> 8)) & 1u) << 4) | (((p >> 7) & 1u) << 5) | (((p >> 8) & 1u) << 6);
    return p ^ b;
}

// ---------------------------------------------------------------------------
// split / convert weights to bf16 (hi [+ lo residual])
// ---------------------------------------------------------------------------
__global__ __launch_bounds__(256) void split_w(const float* __restrict__ x,
                                               u16* __restrict__ hi, u16* __restrict__ lo, int n4) {
    int i = blockIdx.x * blockDim.x + threadIdx.x;
    int stride = gridDim.x * blockDim.x;
    for (; i < n4; i += stride) {
        float4 f = ((const float4*)x)[i];
        float v[4] = {f.x, f.y, f.z, f.w};
        us4 h, l;
#pragma unroll
        for (int j = 0; j < 4; ++j) {
            u16 hh = f2b(v[j]);
            h[j] = hh;
            l[j] = f2b(v[j] - b2f(hh));
        }
        ((us4*)hi)[i] = h;
        ((us4*)lo)[i] = l;
    }
}
__global__ __launch_bounds__(256) void cvt_w(const float* __restrict__ x, u16* __restrict__ hi, int n4) {
    int i = blockIdx.x * blockDim.x + threadIdx.x;
    int stride = gridDim.x * blockDim.x;
    for (; i < n4; i += stride) {
        float4 f = ((const float4*)x)[i];
        us4 h;
        h[0] = f2b(f.x); h[1] = f2b(f.y); h[2] = f2b(f.z); h[3] = f2b(f.w);
        ((us4*)hi)[i] = h;
    }
}

// ---------------------------------------------------------------------------
// GEMM  Y[M,N] = X[M,K] @ W[N,K]^T (+bias).  M=8192, N=K=1024.
// 128x128 tile, BK=32, 4 waves, 4x4 16x16x32 frags/wave.
// TERMS=3: split-bf16 (hh+hl+lh) for f32-accurate product.
// XMODE=0: X is f32, reg-staged + split on the fly. XMODE=1: X bf16 via gload_lds.
// OMODE: 0=f32, 1=bf16, 2=f32+bias
// ---------------------------------------------------------------------------
template <int TERMS, int XMODE, int OMODE>
__global__ __launch_bounds__(256) void gemm_mfma(
    const float* __restrict__ Xf, const u16* __restrict__ Xb,
    const u16* __restrict__ Wh, const u16* __restrict__ Wl,
    const float* __restrict__ bias, float* __restrict__ Of, u16* __restrict__ Ob) {
    constexpr u32 OFF_AH = 0, OFF_BH = 8192, OFF_AL = 16384, OFF_BL = 24576;
    __shared__ __align__(16) char smem[(TERMS == 3) ? 32768 : 16384];

    // XCD-aware swizzle (512 blocks, 512%8==0 -> simple bijection)
    u32 bid = blockIdx.x;
    u32 wg = (bid & 7) * 64 + (bid >> 3);
    const u32 m0 = (wg >> 3) * 128, n0 = (wg & 7) * 128;

    const int tid = threadIdx.x;
    const int w = tid >> 6, lane = tid & 63, c = lane & 15, g = lane >> 4;
    const int wr = w >> 1, wc = w & 1;

    u32 pa[4], pb[4];
#pragma unroll
    for (int i = 0; i < 4; ++i) {
        pa[i] = swz((u32)(wr * 64 + i * 16 + c) * 64 + (u32)g * 16);
        pb[i] = swz((u32)(wc * 64 + i * 16 + c) * 64 + (u32)g * 16);
    }

    f32x4 acc[4][4];
#pragma unroll
    for (int i = 0; i < 4; ++i)
#pragma unroll
        for (int j = 0; j < 4; ++j) acc[i][j] = f32x4{0.f, 0.f, 0.f, 0.f};

    for (int kb = 0; kb < HID / 32; ++kb) {
        const int koff = kb * 32;
        // ---- stage W (and X when bf16) via global_load_lds, source pre-unswizzled ----
        {
            const int nW = (TERMS == 3) ? 16 : 8;
            const int total = nW + ((XMODE == 1) ? 8 : 0);
            for (int id = w; id < total; id += 4) {
                u32 p = (u32)(id & 7) * 1024 + (u32)lane * 16;
                u32 L = unswz(p);
                u32 row = L >> 6, colb = L & 63;
                const char* src;
                u32 loff;
                if (id < 8) {
                    src = (const char*)Wh + ((size_t)(n0 + row)) * 2048 + (size_t)koff * 2 + colb;
                    loff = OFF_BH + (p & 0xFFFFFC00u);
                } else if (TERMS == 3 && id < 16) {
                    src = (const char*)Wl + ((size_t)(n0 + row)) * 2048 + (size_t)koff * 2 + colb;
                    loff = OFF_BL + (p & 0xFFFFFC00u);
                } else {
                    src = (const char*)Xb + ((size_t)(m0 + row)) * 2048 + (size_t)koff * 2 + colb;
                    loff = OFF_AH + (p & 0xFFFFFC00u);
                }
                gl_lds16(src, smem + loff);
            }
        }
        // ---- stage X from f32 with on-the-fly hi/lo split ----
        if (XMODE == 0) {
            const int row = tid >> 1, half = tid & 1;
            const float* xr = Xf + ((size_t)(m0 + row)) * HID + koff + half * 16;
            float4 f0 = ((const float4*)xr)[0], f1 = ((const float4*)xr)[1],
                   f2 = ((const float4*)xr)[2], f3 = ((const float4*)xr)[3];
            float v[16] = {f0.x, f0.y, f0.z, f0.w, f1.x, f1.y, f1.z, f1.w,
                           f2.x, f2.y, f2.z, f2.w, f3.x, f3.y, f3.z, f3.w};
#pragma unroll
            for (int s = 0; s < 2; ++s) {
                us8 h, l8;
#pragma unroll
                for (int i = 0; i < 8; ++i) {
                    u16 hh = f2b(v[s * 8 + i]);
                    h[i] = hh;
                    if (TERMS == 3) l8[i] = f2b(v[s * 8 + i] - b2f(hh));
                }
                u32 ph = swz((u32)row * 64 + (u32)half * 32 + (u32)s * 16);
                *(us8*)(smem + OFF_AH + ph) = h;
                if (TERMS == 3) *(us8*)(smem + OFF_AL + ph) = l8;
            }
        }
        __syncthreads();
        // ---- MFMA ----
        bfrag ah[4], al[4];
#pragma unroll
        for (int mi = 0; mi < 4; ++mi) {
            ah[mi] = *(const bfrag*)(smem + OFF_AH + pa[mi]);
            if (TERMS == 3) al[mi] = *(const bfrag*)(smem + OFF_AL + pa[mi]);
        }
#pragma unroll
        for (int ni = 0; ni < 4; ++ni) {
            bfrag bh = *(const bfrag*)(smem + OFF_BH + pb[ni]);
            bfrag bl;
            if (TERMS == 3) bl = *(const bfrag*)(smem + OFF_BL + pb[ni]);
#pragma unroll
            for (int mi = 0; mi < 4; ++mi) {
                acc[mi][ni] = __builtin_amdgcn_mfma_f32_16x16x32_bf16(ah[mi], bh, acc[mi][ni], 0, 0, 0);
                if (TERMS == 3) {
                    acc[mi][ni] = __builtin_amdgcn_mfma_f32_16x16x32_bf16(ah[mi], bl, acc[mi][ni], 0, 0, 0);
                    acc[mi][ni] = __builtin_amdgcn_mfma_f32_16x16x32_bf16(al[mi], bh, acc[mi][ni], 0, 0, 0);
                }
            }
        }
        __syncthreads();
    }
    // ---- epilogue (C/D: col = lane&15, row = 4*(lane>>4)+reg) ----
#pragma unroll
    for (int mi = 0; mi < 4; ++mi) {
#pragma unroll
        for (int ni = 0; ni < 4; ++ni) {
            const u32 n = n0 + wc * 64 + ni * 16 + c;
            float bv = (OMODE == 2) ? bias[n] : 0.f;
#pragma unroll
            for (int r = 0; r < 4; ++r) {
                const size_t m = m0 + wr * 64 + mi * 16 + 4 * g + r;
                float val = acc[mi][ni][r] + bv;
                if (OMODE == 1) Ob[m * HID + n] = f2b(val);
                else Of[m * HID + n] = val;
            }
        }
    }
}

// ---------------------------------------------------------------------------
// Flash attention, MFMA. Block = (b, head, 64 Q rows), 4 waves (16 rows each).
// QK^T split-bf16 (3 MFMA); online softmax in regs (16-lane shfl row-reduce);
// P via LDS (reuses K_hi buf); V transpose-staged (reuses K_lo buf) with
// granule-XOR to break the write conflict. All tiles pitch 72.
// ---------------------------------------------------------------------------
__global__ __launch_bounds__(256) void attn_mfma(
    const float* __restrict__ Qf, const float* __restrict__ Kf,
    const u16* __restrict__ Vb, u16* __restrict__ Cc) {
    __shared__ __align__(16) u16 Qh[64 * 72], Ql[64 * 72], KP[64 * 72], KV[64 * 72];

    u32 bid = blockIdx.x;
    u32 wg = (bid & 7) * 256 + (bid >> 3);   // 2048 blocks, XCD-chunked
    const int b = wg >> 8;
    const int head = (wg >> 4) & 15;
    const int q0 = (wg & 15) * 64;

    const int tid = threadIdx.x;
    const int w = tid >> 6, lane = tid & 63, c = lane & 15, g = lane >> 4;

    // ---- stage Q tile (hi/lo) ----
    {
        const int row = tid >> 2, cs = tid & 3;
        const float* qr = Qf + ((size_t)(b * SEQ + q0 + row)) * HID + head * DH + cs * 16;
        float4 f0 = ((const float4*)qr)[0], f1 = ((const float4*)qr)[1],
               f2 = ((const float4*)qr)[2], f3 = ((const float4*)qr)[3];
        float v[16] = {f0.x, f0.y, f0.z, f0.w, f1.x, f1.y, f1.z, f1.w,
                       f2.x, f2.y, f2.z, f2.w, f3.x, f3.y, f3.z, f3.w};
#pragma unroll
        for (int s = 0; s < 2; ++s) {
            us8 h, l8;
#pragma unroll
            for (int i = 0; i < 8; ++i) {
                u16 hh = f2b(v[s * 8 + i]);
                h[i] = hh;
                l8[i] = f2b(v[s * 8 + i] - b2f(hh));
            }
            *(us8*)(Qh + row * 72 + cs * 16 + s * 8) = h;
            *(us8*)(Ql + row * 72 + cs * 16 + s * 8) = l8;
        }
    }

    float m_[4] = {-1e30f, -1e30f, -1e30f, -1e30f};
    float l_[4] = {0.f, 0.f, 0.f, 0.f};
    f32x4 acc[4];
#pragma unroll
    for (int j = 0; j < 4; ++j) acc[j] = f32x4{0.f, 0.f, 0.f, 0.f};

    for (int kc = 0; kc < SEQ / 64; ++kc) {
        __syncthreads();   // prior PV done (and Q staged, first iter)
        // ---- stage K chunk: hi->KP, lo->KV ----
        {
            const int row = tid >> 2, cs = tid & 3;
            const float* kr = Kf + ((size_t)(b * SEQ + kc * 64 + row)) * HID + head * DH + cs * 16;
            float4 f0 = ((const float4*)kr)[0], f1 = ((const float4*)kr)[1],
                   f2 = ((const float4*)kr)[2], f3 = ((const float4*)kr)[3];
            float v[16] = {f0.x, f0.y, f0.z, f0.w, f1.x, f1.y, f1.z, f1.w,
                           f2.x, f2.y, f2.z, f2.w, f3.x, f3.y, f3.z, f3.w};
#pragma unroll
            for (int s = 0; s < 2; ++s) {
                us8 h, l8;
#pragma unroll
                for (int i = 0; i < 8; ++i) {
                    u16 hh = f2b(v[s * 8 + i]);
                    h[i] = hh;
                    l8[i] = f2b(v[s * 8 + i] - b2f(hh));
                }
                *(us8*)(KP + row * 72 + cs * 16 + s * 8) = h;
                *(us8*)(KV + row * 72 + cs * 16 + s * 8) = l8;
            }
        }
        __syncthreads();
        // ---- S = Q K^T (rows w*16..+15) ----
        f32x4 s4[4];
#pragma unroll
        for (int j = 0; j < 4; ++j) s4[j] = f32x4{0.f, 0.f, 0.f, 0.f};
#pragma unroll
        for (int ks = 0; ks < 2; ++ks) {
            bfrag ah = *(const bfrag*)(Qh + (w * 16 + c) * 72 + ks * 32 + g * 8);
            bfrag al = *(const bfrag*)(Ql + (w * 16 + c) * 72 + ks * 32 + g * 8);
#pragma unroll
            for (int jf = 0; jf < 4; ++jf) {
                bfrag bh = *(const bfrag*)(KP + (jf * 16 + c) * 72 + ks * 32 + g * 8);
                bfrag bl = *(const bfrag*)(KV + (jf * 16 + c) * 72 + ks * 32 + g * 8);
                s4[jf] = __builtin_amdgcn_mfma_f32_16x16x32_bf16(ah, bh, s4[jf], 0, 0, 0);
                s4[jf] = __builtin_amdgcn_mfma_f32_16x16x32_bf16(ah, bl, s4[jf], 0, 0, 0);
                s4[jf] = __builtin_amdgcn_mfma_f32_16x16x32_bf16(al, bh, s4[jf], 0, 0, 0);
            }
        }
        __syncthreads();   // all QK reads done; KP/KV reusable
        // ---- online softmax (row = w*16 + 4g + r, cols jf*16+c) + P->KP ----
        float scl[4];
#pragma unroll
        for (int r = 0; r < 4; ++r) {
            float v0 = s4[0][r] * 0.125f, v1 = s4[1][r] * 0.125f,
                  v2 = s4[2][r] * 0.125f, v3 = s4[3][r] * 0.125f;
            float rm = fmaxf(fmaxf(v0, v1), fmaxf(v2, v3));
            rm = fmaxf(rm, __shfl_xor(rm, 1));
            rm = fmaxf(rm, __shfl_xor(rm, 2));
            rm = fmaxf(rm, __shfl_xor(rm, 4));
            rm = fmaxf(rm, __shfl_xor(rm, 8));
            float mn = fmaxf(m_[r], rm);
            scl[r] = __expf(m_[r] - mn);
            float p0 = __expf(v0 - mn), p1 = __expf(v1 - mn),
                  p2 = __expf(v2 - mn), p3 = __expf(v3 - mn);
            float rs = p0 + p1 + p2 + p3;
            rs += __shfl_xor(rs, 1);
            rs += __shfl_xor(rs, 2);
            rs += __shfl_xor(rs, 4);
            rs += __shfl_xor(rs, 8);
            l_[r] = l_[r] * scl[r] + rs;
            m_[r] = mn;
            const int prow = (w * 16 + 4 * g + r) * 72;
            KP[prow + 0 + c] = f2b(p0);
            KP[prow + 16 + c] = f2b(p1);
            KP[prow + 32 + c] = f2b(p2);
            KP[prow + 48 + c] = f2b(p3);
        }
#pragma unroll
        for (int jd = 0; jd < 4; ++jd) {
            f32x4 t = acc[jd];
            t[0] *= scl[0]; t[1] *= scl[1]; t[2] *= scl[2]; t[3] *= scl[3];
            acc[jd] = t;
        }
        // ---- stage V transposed into KV: Vt[d][k], granule-XOR on k ----
#pragma unroll
        for (int it = 0; it < 2; ++it) {
            const int idx = tid + it * 256;
            const int k = idx >> 3, ds = idx & 7, d0 = ds * 8;
            const u16* vr = Vb + ((size_t)(b * SEQ + kc * 64 + k)) * HID + head * DH + d0;
            us8 vv = *(const us8*)vr;
            const u32 kg = (((u32)(k >> 3)) ^ ((u32)ds & 3u)) << 3;
#pragma unroll
            for (int i = 0; i < 8; ++i) KV[(d0 + i) * 72 + kg + (k & 7)] = vv[i];
        }
        __syncthreads();   // P and Vt visible
        // ---- O += P V ----
#pragma unroll
        for (int ks = 0; ks < 2; ++ks) {
            bfrag ap = *(const bfrag*)(KP + (w * 16 + c) * 72 + ks * 32 + g * 8);
#pragma unroll
            for (int jd = 0; jd < 4; ++jd) {
                const int d = jd * 16 + c;
                const u32 G = (u32)(ks * 4 + g);
                const u32 key = (u32)((d >> 3) & 3);
                bfrag bv = *(const bfrag*)(KV + d * 72 + ((G ^ key) << 3));
                acc[jd] = __builtin_amdgcn_mfma_f32_16x16x32_bf16(ap, bv, acc[jd], 0, 0, 0);
            }
        }
    }
    // ---- normalize + write concat (bf16) ----
    float inv[4] = {1.f / l_[0], 1.f / l_[1], 1.f / l_[2], 1.f / l_[3]};
#pragma unroll
    for (int jd = 0; jd < 4; ++jd) {
#pragma unroll
        for (int r = 0; r < 4; ++r) {
            Cc[((size_t)(b * SEQ + q0 + w * 16 + 4 * g + r)) * HID + head * DH + jd * 16 + c] =
                f2b(acc[jd][r] * inv[r]);
        }
    }
}

// ---------------------------------------------------------------------------
extern "C" void kernel_launch(void* const* d_in, const int* in_sizes, int n_in,
                              void* d_out, int out_size, void* d_ws, size_t ws_size,
                              hipStream_t stream) {
    const float* dec = (const float*)d_in[0];
    const float* enc = (const float*)d_in[1];
    const float* Wq = (const float*)d_in[2];
    const float* Wk = (const float*)d_in[3];
    const float* Wv = (const float*)d_in[4];
    const float* Wo = (const float*)d_in[5];
    const float* bo = (const float*)d_in[6];
    float* out = (float*)d_out;

    char* ws = (char*)d_ws;
    float* Qf = (float*)ws;                               // 32 MiB
    float* Kf = (float*)(ws + (size_t)(32u << 20));       // 32 MiB
    u16* Vb = (u16*)(ws + (size_t)(64u << 20));           // 16 MiB
    u16* Cc = (u16*)(ws + (size_t)(80u << 20));           // 16 MiB
    u16* Wqh = (u16*)(ws + (size_t)(96u << 20));          // 6 x 2 MiB
    u16* Wql = Wqh + (1u << 20);
    u16* Wkh = Wql + (1u << 20);
    u16* Wkl = Wkh + (1u << 20);
    u16* Wvh = Wkl + (1u << 20);
    u16* Woh = Wvh + (1u << 20);                          // total 108 MiB

    const int n4w = HID * HID / 4;
    split_w<<<512, 256, 0, stream>>>(Wq, Wqh, Wql, n4w);
    split_w<<<512, 256, 0, stream>>>(Wk, Wkh, Wkl, n4w);
    cvt_w<<<512, 256, 0, stream>>>(Wv, Wvh, n4w);
    cvt_w<<<512, 256, 0, stream>>>(Wo, Woh, n4w);

    gemm_mfma<3, 0, 0><<<512, 256, 0, stream>>>(dec, nullptr, Wqh, Wql, nullptr, Qf, nullptr);
    gemm_mfma<3, 0, 0><<<512, 256, 0, stream>>>(enc, nullptr, Wkh, Wkl, nullptr, Kf, nullptr);
    gemm_mfma<1, 0, 1><<<512, 256, 0, stream>>>(enc, nullptr, Wvh, nullptr, nullptr, nullptr, Vb);

    attn_mfma<<<2048, 256, 0, stream>>>(Qf, Kf, Vb, Cc);

    gemm_mfma<1, 1, 2><<<512, 256, 0, stream>>>(nullptr, Cc, Woh, nullptr, bo, out, nullptr);
}

// Round 4
// 462.124 us; speedup vs baseline: 3.4392x; 1.0574x over previous
//
#include <hip/hip_runtime.h>
#include <math.h>

#define HID 1024
#define NH 16
#define DH 64
#define BATCH 8
#define SEQ 1024
#define MTOT (BATCH * SEQ) /* 8192 */

typedef __attribute__((ext_vector_type(8))) short bfrag;   // 8 bf16 MFMA operand
typedef __attribute__((ext_vector_type(4))) float f32x4;   // MFMA accumulator
typedef __attribute__((ext_vector_type(8))) unsigned short us8;
typedef __attribute__((ext_vector_type(4))) unsigned short us4;
typedef unsigned int u32;
typedef unsigned short u16;

#define SCALE_Q 0.18033688011112042f   /* 0.125 * log2(e): exp2-domain softmax */

__device__ __forceinline__ u16 f2b(float f) {              // f32 -> bf16 RNE
    u32 u = __float_as_uint(f);
    return (u16)((u + 0x7FFFu + ((u >> 16) & 1u)) >> 16);
}
__device__ __forceinline__ float b2f(u16 h) { return __uint_as_float(((u32)h) << 16); }

__device__ __forceinline__ void gl_lds16(const void* g, void* l) {
    __builtin_amdgcn_global_load_lds(
        (const __attribute__((address_space(1))) unsigned int*)g,
        (__attribute__((address_space(3))) unsigned int*)l, 16, 0, 0);
}

// --- GEMM tile swizzle (64B logical rows), proven in R1 ---
__device__ __forceinline__ u32 swz(u32 L) { return L ^ (((L >> 6) & 7u) << 4); }
__device__ __forceinline__ u32 unswz(u32 p) {
    u32 b = ((((p >> 6) ^ (p >> 8)) & 1u) << 4) | (((p >> 7) & 1u) << 5) | (((p >> 8) & 1u) << 6);
    return p ^ b;
}
// --- attn tile swizzle (128B rows): bits 7-9 -> 4-6, disjoint => involution ---
__device__ __forceinline__ u32 swz128(u32 L) { return L ^ (((L >> 7) & 7u) << 4); }

// ---------------------------------------------------------------------------
// prep: enc -> Eh (bf16); Wq,Wk -> hi/lo split; Wv,Wo -> bf16. One launch.
// ---------------------------------------------------------------------------
__global__ __launch_bounds__(256) void prep(
    const float* __restrict__ enc,
    const float* __restrict__ Wq, const float* __restrict__ Wk,
    const float* __restrict__ Wv, const float* __restrict__ Wo,
    u16* __restrict__ Eh,
    u16* __restrict__ Wqh, u16* __restrict__ Wql,
    u16* __restrict__ Wkh, u16* __restrict__ Wkl,
    u16* __restrict__ Wvh, u16* __restrict__ Woh)
{
    const int NX4 = MTOT * HID / 4;   // 2,097,152
    const int NW4 = HID * HID / 4;    // 262,144
    const int total = NX4 + 4 * NW4;
    for (int i = blockIdx.x * blockDim.x + threadIdx.x; i < total;
         i += gridDim.x * blockDim.x) {
        if (i < NX4) {
            float4 f = ((const float4*)enc)[i];
            us4 h;
            h[0] = f2b(f.x); h[1] = f2b(f.y); h[2] = f2b(f.z); h[3] = f2b(f.w);
            ((us4*)Eh)[i] = h;
        } else {
            int j = i - NX4;
            int rgn = j / NW4, k = j - rgn * NW4;
            const float* src = (rgn == 0) ? Wq : (rgn == 1) ? Wk : (rgn == 2) ? Wv : Wo;
            float4 f = ((const float4*)src)[k];
            float v[4] = {f.x, f.y, f.z, f.w};
            us4 h, l;
#pragma unroll
            for (int q = 0; q < 4; ++q) {
                u16 hh = f2b(v[q]);
                h[q] = hh;
                l[q] = f2b(v[q] - b2f(hh));
            }
            if (rgn == 0) { ((us4*)Wqh)[k] = h; ((us4*)Wql)[k] = l; }
            else if (rgn == 1) { ((us4*)Wkh)[k] = h; ((us4*)Wkl)[k] = l; }
            else if (rgn == 2) { ((us4*)Wvh)[k] = h; }
            else { ((us4*)Woh)[k] = h; }
        }
    }
}

// ---------------------------------------------------------------------------
// GEMM  Y[M,N] = X[M,K] @ W[N,K]^T.  M=8192, N=K=1024.
// 128x128 tile, BK=32, 4 waves, 4x4 16x16x32 frags/wave.
// TERMS=3: split-bf16 (hh+hl+lh). XMODE 0: X f32 reg-split; 1: X bf16 gl_lds.
// EPI 0: f32+bias -> Of. EPI 2: scale+split -> O1(hi),O2(lo) at [b,h,s,d].
// EPI 3: bf16 -> O1 at [b,h,d,s] (V^T).
// ---------------------------------------------------------------------------
template <int TERMS, int XMODE, int EPI>
__global__ __launch_bounds__(256) void gemm_mfma(
    const float* __restrict__ Xf, const u16* __restrict__ Xb,
    const u16* __restrict__ Wh, const u16* __restrict__ Wl,
    const float* __restrict__ bias, float scale,
    float* __restrict__ Of, u16* __restrict__ O1, u16* __restrict__ O2)
{
    constexpr u32 OFF_AH = 0, OFF_BH = 8192, OFF_AL = 16384, OFF_BL = 24576;
    __shared__ __align__(16) char smem[(TERMS == 3) ? 32768 : 16384];

    u32 bid = blockIdx.x;
    u32 wg = (bid & 7) * 64 + (bid >> 3);     // 512 blocks, XCD-chunked
    const u32 m0 = (wg >> 3) * 128, n0 = (wg & 7) * 128;

    const int tid = threadIdx.x;
    const int w = tid >> 6, lane = tid & 63, c = lane & 15, g = lane >> 4;
    const int wr = w >> 1, wc = w & 1;

    u32 pa[4], pb[4];
#pragma unroll
    for (int i = 0; i < 4; ++i) {
        pa[i] = swz((u32)(wr * 64 + i * 16 + c) * 64 + (u32)g * 16);
        pb[i] = swz((u32)(wc * 64 + i * 16 + c) * 64 + (u32)g * 16);
    }

    f32x4 acc[4][4];
#pragma unroll
    for (int i = 0; i < 4; ++i)
#pragma unroll
        for (int j = 0; j < 4; ++j) acc[i][j] = f32x4{0.f, 0.f, 0.f, 0.f};

    for (int kb = 0; kb < HID / 32; ++kb) {
        const int koff = kb * 32;
        // ---- gl_lds staging: B tiles (+A when bf16), source pre-unswizzled ----
        {
            const int nB = (TERMS == 3) ? 16 : 8;
            const int total = nB + ((XMODE == 1) ? 8 : 0);
            for (int id = w; id < total; id += 4) {
                u32 p = (u32)(id & 7) * 1024 + (u32)lane * 16;
                u32 L = unswz(p);
                u32 row = L >> 6, colb = L & 63;
                const char* src;
                u32 loff;
                if (id < 8) {
                    src = (const char*)Wh + ((size_t)(n0 + row)) * 2048 + (size_t)koff * 2 + colb;
                    loff = OFF_BH + (p & 0xFFFFFC00u);
                } else if (TERMS == 3 && id < 16) {
                    src = (const char*)Wl + ((size_t)(n0 + row)) * 2048 + (size_t)koff * 2 + colb;
                    loff = OFF_BL + (p & 0xFFFFFC00u);
                } else {
                    src = (const char*)Xb + ((size_t)(m0 + row)) * 2048 + (size_t)koff * 2 + colb;
                    loff = OFF_AH + (p & 0xFFFFFC00u);
                }
                gl_lds16(src, smem + loff);
            }
        }
        // ---- X f32 reg-staged with on-the-fly hi/lo split ----
        if (XMODE == 0) {
            const int row = tid >> 1, half = tid & 1;
            const float* xr = Xf + ((size_t)(m0 + row)) * HID + koff + half * 16;
            float4 f0 = ((const float4*)xr)[0], f1 = ((const float4*)xr)[1],
                   f2 = ((const float4*)xr)[2], f3 = ((const float4*)xr)[3];
            float v[16] = {f0.x, f0.y, f0.z, f0.w, f1.x, f1.y, f1.z, f1.w,
                           f2.x, f2.y, f2.z, f2.w, f3.x, f3.y, f3.z, f3.w};
#pragma unroll
            for (int s = 0; s < 2; ++s) {
                us8 h, l8;
#pragma unroll
                for (int i = 0; i < 8; ++i) {
                    u16 hh = f2b(v[s * 8 + i]);
                    h[i] = hh;
                    if (TERMS == 3) l8[i] = f2b(v[s * 8 + i] - b2f(hh));
                }
                u32 ph = swz((u32)row * 64 + (u32)half * 32 + (u32)s * 16);
                *(us8*)(smem + OFF_AH + ph) = h;
                if (TERMS == 3) *(us8*)(smem + OFF_AL + ph) = l8;
            }
        }
        __syncthreads();
        // ---- MFMA ----
        bfrag ah[4], al[4];
#pragma unroll
        for (int mi = 0; mi < 4; ++mi) {
            ah[mi] = *(const bfrag*)(smem + OFF_AH + pa[mi]);
            if (TERMS == 3) al[mi] = *(const bfrag*)(smem + OFF_AL + pa[mi]);
        }
#pragma unroll
        for (int ni = 0; ni < 4; ++ni) {
            bfrag bh = *(const bfrag*)(smem + OFF_BH + pb[ni]);
            bfrag bl;
            if (TERMS == 3) bl = *(const bfrag*)(smem + OFF_BL + pb[ni]);
#pragma unroll
            for (int mi = 0; mi < 4; ++mi) {
                acc[mi][ni] = __builtin_amdgcn_mfma_f32_16x16x32_bf16(ah[mi], bh, acc[mi][ni], 0, 0, 0);
                if (TERMS == 3) {
                    acc[mi][ni] = __builtin_amdgcn_mfma_f32_16x16x32_bf16(ah[mi], bl, acc[mi][ni], 0, 0, 0);
                    acc[mi][ni] = __builtin_amdgcn_mfma_f32_16x16x32_bf16(al[mi], bh, acc[mi][ni], 0, 0, 0);
                }
            }
        }
        __syncthreads();
    }
    // ---- epilogue (C/D: col = lane&15, row = 4*(lane>>4)+reg) ----
#pragma unroll
    for (int mi = 0; mi < 4; ++mi) {
#pragma unroll
        for (int ni = 0; ni < 4; ++ni) {
            const u32 n = n0 + wc * 64 + ni * 16 + c;
            const u32 mb = m0 + wr * 64 + mi * 16 + 4 * g;
            if (EPI == 0) {
                float bv = bias[n];
#pragma unroll
                for (int r = 0; r < 4; ++r)
                    Of[(size_t)(mb + r) * HID + n] = acc[mi][ni][r] + bv;
            } else if (EPI == 2) {
                const u32 h = n >> 6, d = n & 63;
                const u32 b_ = mb >> 10, s = mb & 1023;
                size_t base = ((size_t)(b_ * NH + h) * SEQ + s) * 64 + d;
#pragma unroll
                for (int r = 0; r < 4; ++r) {
                    float v = acc[mi][ni][r] * scale;
                    u16 hh = f2b(v);
                    O1[base + (size_t)r * 64] = hh;
                    O2[base + (size_t)r * 64] = f2b(v - b2f(hh));
                }
            } else {   // EPI 3: V^T [b,h,d,s]
                const u32 h = n >> 6, d = n & 63;
                const u32 b_ = mb >> 10, s = mb & 1023;
                us4 o;
#pragma unroll
                for (int r = 0; r < 4; ++r) o[r] = f2b(acc[mi][ni][r]);
                *(us4*)&O1[((size_t)(b_ * NH + h) * 64 + d) * SEQ + s] = o;
            }
        }
    }
}

// ---------------------------------------------------------------------------
// Flash attention, MFMA, all-bf16 gl_lds staging.
// Block = (b, head, 64 Q rows), 4 waves (16 q-rows each).
// Q pre-scaled by 0.125*log2e -> exp2-domain softmax.
// LDS tiles [64][64] bf16 with 128B-row XOR swizzle; P pitch-72.
// ---------------------------------------------------------------------------
__global__ __launch_bounds__(256) void attn_mfma(
    const u16* __restrict__ Qh, const u16* __restrict__ Ql,
    const u16* __restrict__ Kh, const u16* __restrict__ Kl,
    const u16* __restrict__ Vt, u16* __restrict__ Cc)
{
    __shared__ __align__(16) u16 sQH[4096], sQL[4096], sKH[4096], sKL[4096], sVT[4096];
    __shared__ __align__(16) u16 sP[64 * 72];

    u32 bid = blockIdx.x;
    u32 wg = (bid & 7) * 256 + (bid >> 3);   // 2048 blocks, XCD-chunked
    const int b = wg >> 8;
    const int head = (wg >> 4) & 15;
    const int q0 = (wg & 15) * 64;

    const int tid = threadIdx.x;
    const int w = tid >> 6, lane = tid & 63, c = lane & 15, g = lane >> 4;

    const size_t hb = (size_t)(b * NH + head);
    const char* gQH = (const char*)(Qh + (hb * SEQ + q0) * 64);
    const char* gQL = (const char*)(Ql + (hb * SEQ + q0) * 64);
    const char* gKH = (const char*)(Kh + hb * SEQ * 64);
    const char* gKL = (const char*)(Kl + hb * SEQ * 64);
    const char* gVT = (const char*)(Vt + hb * 64 * SEQ);

    // ---- stage Q tiles once (2 tiles x 8 segs) ----
    for (int t = w; t < 16; t += 4) {
        u32 seg = (u32)(t & 7);
        u32 p = seg * 1024 + (u32)lane * 16;
        u32 ps = swz128(p);
        const char* src = ((t < 8) ? gQH : gQL) + ps;
        u16* dst = ((t < 8) ? sQH : sQL) + seg * 512;
        gl_lds16(src, dst);
    }

    float m_[4] = {-1e30f, -1e30f, -1e30f, -1e30f};
    float l_[4] = {0.f, 0.f, 0.f, 0.f};
    f32x4 acc[4];
#pragma unroll
    for (int j = 0; j < 4; ++j) acc[j] = f32x4{0.f, 0.f, 0.f, 0.f};

    for (int kc = 0; kc < SEQ / 64; ++kc) {
        __syncthreads();   // prior chunk's K/VT reads done
        // ---- stage KH,KL,VT (3 tiles x 8 segs = 24 insts over 4 waves) ----
        for (int t = w; t < 24; t += 4) {
            u32 seg = (u32)(t & 7);
            u32 p = seg * 1024 + (u32)lane * 16;
            u32 ps = swz128(p);
            const char* src;
            u16* dst;
            if (t < 8) {
                src = gKH + (size_t)kc * 8192 + ps;
                dst = sKH + seg * 512;
            } else if (t < 16) {
                src = gKL + (size_t)kc * 8192 + ps;
                dst = sKL + seg * 512;
            } else {
                u32 row = ps >> 7, col = ps & 127;
                src = gVT + (size_t)row * (SEQ * 2) + (size_t)kc * 128 + col;
                dst = sVT + seg * 512;
            }
            gl_lds16(src, dst);
        }
        __syncthreads();   // staged data (incl Q on kc=0) visible

        // ---- S = Q K^T (wave w: q-rows w*16..+15) ----
        f32x4 s4[4];
#pragma unroll
        for (int j = 0; j < 4; ++j) s4[j] = f32x4{0.f, 0.f, 0.f, 0.f};
#pragma unroll
        for (int ks = 0; ks < 2; ++ks) {
            u32 aoff = swz128((u32)(w * 16 + c) * 128 + (u32)ks * 64 + (u32)g * 16);
            bfrag ah = *(const bfrag*)((const char*)sQH + aoff);
            bfrag al = *(const bfrag*)((const char*)sQL + aoff);
#pragma unroll
            for (int jf = 0; jf < 4; ++jf) {
                u32 boff = swz128((u32)(jf * 16 + c) * 128 + (u32)ks * 64 + (u32)g * 16);
                bfrag bh = *(const bfrag*)((const char*)sKH + boff);
                bfrag bl = *(const bfrag*)((const char*)sKL + boff);
                s4[jf] = __builtin_amdgcn_mfma_f32_16x16x32_bf16(ah, bh, s4[jf], 0, 0, 0);
                s4[jf] = __builtin_amdgcn_mfma_f32_16x16x32_bf16(ah, bl, s4[jf], 0, 0, 0);
                s4[jf] = __builtin_amdgcn_mfma_f32_16x16x32_bf16(al, bh, s4[jf], 0, 0, 0);
            }
        }

        // ---- online softmax, base-2 (rows w*16+4g+r; 16 c-lanes share a row) ----
        float scl[4];
#pragma unroll
        for (int r = 0; r < 4; ++r) {
            float v0 = s4[0][r], v1 = s4[1][r], v2 = s4[2][r], v3 = s4[3][r];
            float rm = fmaxf(fmaxf(v0, v1), fmaxf(v2, v3));
            rm = fmaxf(rm, __shfl_xor(rm, 1));
            rm = fmaxf(rm, __shfl_xor(rm, 2));
            rm = fmaxf(rm, __shfl_xor(rm, 4));
            rm = fmaxf(rm, __shfl_xor(rm, 8));
            float mn = fmaxf(m_[r], rm);
            scl[r] = exp2f(m_[r] - mn);
            float p0 = exp2f(v0 - mn), p1 = exp2f(v1 - mn),
                  p2 = exp2f(v2 - mn), p3 = exp2f(v3 - mn);
            float rs = p0 + p1 + p2 + p3;
            rs += __shfl_xor(rs, 1);
            rs += __shfl_xor(rs, 2);
            rs += __shfl_xor(rs, 4);
            rs += __shfl_xor(rs, 8);
            l_[r] = l_[r] * scl[r] + rs;
            m_[r] = mn;
            const int prow = (w * 16 + 4 * g + r) * 72;
            sP[prow + 0 + c] = f2b(p0);
            sP[prow + 16 + c] = f2b(p1);
            sP[prow + 32 + c] = f2b(p2);
            sP[prow + 48 + c] = f2b(p3);
        }
#pragma unroll
        for (int jd = 0; jd < 4; ++jd) {
            f32x4 t = acc[jd];
            t[0] *= scl[0]; t[1] *= scl[1]; t[2] *= scl[2]; t[3] *= scl[3];
            acc[jd] = t;
        }

        // ---- O += P V  (P rows written & read by same wave; VT staged above) ----
#pragma unroll
        for (int ks = 0; ks < 2; ++ks) {
            bfrag ap = *(const bfrag*)(sP + (w * 16 + c) * 72 + ks * 32 + g * 8);
#pragma unroll
            for (int jd = 0; jd < 4; ++jd) {
                u32 voff = swz128((u32)(jd * 16 + c) * 128 + (u32)ks * 64 + (u32)g * 16);
                bfrag bv = *(const bfrag*)((const char*)sVT + voff);
                acc[jd] = __builtin_amdgcn_mfma_f32_16x16x32_bf16(ap, bv, acc[jd], 0, 0, 0);
            }
        }
    }

    // ---- normalize + write concat (bf16, [b, s, h*64+d]) ----
    float inv[4] = {1.f / l_[0], 1.f / l_[1], 1.f / l_[2], 1.f / l_[3]};
#pragma unroll
    for (int jd = 0; jd < 4; ++jd) {
#pragma unroll
        for (int r = 0; r < 4; ++r) {
            Cc[((size_t)(b * SEQ + q0 + w * 16 + 4 * g + r)) * HID + head * DH + jd * 16 + c] =
                f2b(acc[jd][r] * inv[r]);
        }
    }
}

// ---------------------------------------------------------------------------
extern "C" void kernel_launch(void* const* d_in, const int* in_sizes, int n_in,
                              void* d_out, int out_size, void* d_ws, size_t ws_size,
                              hipStream_t stream)
{
    const float* dec = (const float*)d_in[0];
    const float* enc = (const float*)d_in[1];
    const float* Wq = (const float*)d_in[2];
    const float* Wk = (const float*)d_in[3];
    const float* Wv = (const float*)d_in[4];
    const float* Wo = (const float*)d_in[5];
    const float* bo = (const float*)d_in[6];
    float* out = (float*)d_out;

    char* ws = (char*)d_ws;
    const size_t MB = 1u << 20;
    u16* Eh  = (u16*)ws;                       // 16 MiB   (aliased by Cc later)
    u16* Qhg = (u16*)(ws + 16 * MB);           // 16 MiB
    u16* Qlg = (u16*)(ws + 32 * MB);           // 16 MiB
    u16* Khg = (u16*)(ws + 48 * MB);           // 16 MiB
    u16* Klg = (u16*)(ws + 64 * MB);           // 16 MiB
    u16* Vtg = (u16*)(ws + 80 * MB);           // 16 MiB
    u16* Wqh = (u16*)(ws + 96 * MB);           // 6 x 2 MiB weights
    u16* Wql = Wqh + (1u << 20);
    u16* Wkh = Wql + (1u << 20);
    u16* Wkl = Wkh + (1u << 20);
    u16* Wvh = Wkl + (1u << 20);
    u16* Woh = Wvh + (1u << 20);               // total 108 MiB
    u16* Cc  = Eh;                             // Eh dead after V-GEMM

    prep<<<2048, 256, 0, stream>>>(enc, Wq, Wk, Wv, Wo,
                                   Eh, Wqh, Wql, Wkh, Wkl, Wvh, Woh);

    // Q: scale folded (0.125*log2e), split hi/lo, head-major
    gemm_mfma<3, 0, 2><<<512, 256, 0, stream>>>(dec, nullptr, Wqh, Wql, nullptr,
                                                SCALE_Q, nullptr, Qhg, Qlg);
    // K: split hi/lo, head-major
    gemm_mfma<3, 0, 2><<<512, 256, 0, stream>>>(enc, nullptr, Wkh, Wkl, nullptr,
                                                1.0f, nullptr, Khg, Klg);
    // V: bf16 A via gl_lds, V^T output
    gemm_mfma<1, 1, 3><<<512, 256, 0, stream>>>(nullptr, Eh, Wvh, nullptr, nullptr,
                                                1.0f, nullptr, Vtg, nullptr);

    attn_mfma<<<2048, 256, 0, stream>>>(Qhg, Qlg, Khg, Klg, Vtg, Cc);

    // O: bf16 A via gl_lds, f32 + bias
    gemm_mfma<1, 1, 0><<<512, 256, 0, stream>>>(nullptr, Cc, Woh, nullptr, bo,
                                                1.0f, out, nullptr, nullptr);
}

// Round 5
// 417.364 us; speedup vs baseline: 3.8080x; 1.1072x over previous
//
#include <hip/hip_runtime.h>
#include <hip/hip_bf16.h>
#include <math.h>

#define HID 1024
#define NH 16
#define DH 64
#define BATCH 8
#define SEQ 1024
#define MTOT (BATCH * SEQ) /* 8192 */

typedef __attribute__((ext_vector_type(8))) short bfrag;   // 8 bf16 MFMA operand
typedef __attribute__((ext_vector_type(4))) float f32x4;   // MFMA accumulator
typedef __attribute__((ext_vector_type(8))) unsigned short us8;
typedef __attribute__((ext_vector_type(4))) unsigned short us4;
typedef __attribute__((ext_vector_type(2))) unsigned int u32x2;
typedef unsigned int u32;
typedef unsigned short u16;

#define SCALE_Q 0.18033688011112042f   /* 0.125 * log2(e): exp2-domain softmax */

__device__ __forceinline__ u16 f2b(float f) {              // f32 -> bf16 RNE
    u32 u = __float_as_uint(f);
    return (u16)((u + 0x7FFFu + ((u >> 16) & 1u)) >> 16);
}
__device__ __forceinline__ float b2f(u16 h) { return __uint_as_float(((u32)h) << 16); }

__device__ __forceinline__ u32 packbf(float a, float b) {  // 2xf32 -> packed bf16 (cvt_pk)
    __hip_bfloat162 t = __float22bfloat162_rn(float2{a, b});
    u32 r;
    __builtin_memcpy(&r, &t, 4);
    return r;
}

__device__ __forceinline__ void gl_lds16(const void* g, void* l) {
    __builtin_amdgcn_global_load_lds(
        (const __attribute__((address_space(1))) unsigned int*)g,
        (__attribute__((address_space(3))) unsigned int*)l, 16, 0, 0);
}

// --- GEMM tile swizzle (64B logical rows), proven in R1 ---
__device__ __forceinline__ u32 swz(u32 L) { return L ^ (((L >> 6) & 7u) << 4); }
__device__ __forceinline__ u32 unswz(u32 p) {
    u32 b = ((((p >> 6) ^ (p >> 8)) & 1u) << 4) | (((p >> 7) & 1u) << 5) | (((p >> 8) & 1u) << 6);
    return p ^ b;
}
// --- attn tile swizzle (128B rows): bits 7-9 -> 4-6, disjoint => involution ---
__device__ __forceinline__ u32 swz128(u32 L) { return L ^ (((L >> 7) & 7u) << 4); }

// ---------------------------------------------------------------------------
// prep: enc -> Eh (bf16); Wq,Wk -> hi/lo split; Wv,Wo -> bf16. One launch.
// ---------------------------------------------------------------------------
__global__ __launch_bounds__(256) void prep(
    const float* __restrict__ enc,
    const float* __restrict__ Wq, const float* __restrict__ Wk,
    const float* __restrict__ Wv, const float* __restrict__ Wo,
    u16* __restrict__ Eh,
    u16* __restrict__ Wqh, u16* __restrict__ Wql,
    u16* __restrict__ Wkh, u16* __restrict__ Wkl,
    u16* __restrict__ Wvh, u16* __restrict__ Woh)
{
    const int NX4 = MTOT * HID / 4;   // 2,097,152
    const int NW4 = HID * HID / 4;    // 262,144
    const int total = NX4 + 4 * NW4;
    for (int i = blockIdx.x * blockDim.x + threadIdx.x; i < total;
         i += gridDim.x * blockDim.x) {
        if (i < NX4) {
            float4 f = ((const float4*)enc)[i];
            us4 h;
            h[0] = f2b(f.x); h[1] = f2b(f.y); h[2] = f2b(f.z); h[3] = f2b(f.w);
            ((us4*)Eh)[i] = h;
        } else {
            int j = i - NX4;
            int rgn = j / NW4, k = j - rgn * NW4;
            const float* src = (rgn == 0) ? Wq : (rgn == 1) ? Wk : (rgn == 2) ? Wv : Wo;
            float4 f = ((const float4*)src)[k];
            float v[4] = {f.x, f.y, f.z, f.w};
            us4 h, l;
#pragma unroll
            for (int q = 0; q < 4; ++q) {
                u16 hh = f2b(v[q]);
                h[q] = hh;
                l[q] = f2b(v[q] - b2f(hh));
            }
            if (rgn == 0) { ((us4*)Wqh)[k] = h; ((us4*)Wql)[k] = l; }
            else if (rgn == 1) { ((us4*)Wkh)[k] = h; ((us4*)Wkl)[k] = l; }
            else if (rgn == 2) { ((us4*)Wvh)[k] = h; }
            else { ((us4*)Woh)[k] = h; }
        }
    }
}

// ---------------------------------------------------------------------------
// GEMM  Y[M,N] = X[M,K] @ W[N,K]^T.  (unchanged from R4 — verified)
// ---------------------------------------------------------------------------
template <int TERMS, int XMODE, int EPI>
__global__ __launch_bounds__(256) void gemm_mfma(
    const float* __restrict__ Xf, const u16* __restrict__ Xb,
    const u16* __restrict__ Wh, const u16* __restrict__ Wl,
    const float* __restrict__ bias, float scale,
    float* __restrict__ Of, u16* __restrict__ O1, u16* __restrict__ O2)
{
    constexpr u32 OFF_AH = 0, OFF_BH = 8192, OFF_AL = 16384, OFF_BL = 24576;
    __shared__ __align__(16) char smem[(TERMS == 3) ? 32768 : 16384];

    u32 bid = blockIdx.x;
    u32 wg = (bid & 7) * 64 + (bid >> 3);     // 512 blocks, XCD-chunked
    const u32 m0 = (wg >> 3) * 128, n0 = (wg & 7) * 128;

    const int tid = threadIdx.x;
    const int w = tid >> 6, lane = tid & 63, c = lane & 15, g = lane >> 4;
    const int wr = w >> 1, wc = w & 1;

    u32 pa[4], pb[4];
#pragma unroll
    for (int i = 0; i < 4; ++i) {
        pa[i] = swz((u32)(wr * 64 + i * 16 + c) * 64 + (u32)g * 16);
        pb[i] = swz((u32)(wc * 64 + i * 16 + c) * 64 + (u32)g * 16);
    }

    f32x4 acc[4][4];
#pragma unroll
    for (int i = 0; i < 4; ++i)
#pragma unroll
        for (int j = 0; j < 4; ++j) acc[i][j] = f32x4{0.f, 0.f, 0.f, 0.f};

    for (int kb = 0; kb < HID / 32; ++kb) {
        const int koff = kb * 32;
        {
            const int nB = (TERMS == 3) ? 16 : 8;
            const int total = nB + ((XMODE == 1) ? 8 : 0);
            for (int id = w; id < total; id += 4) {
                u32 p = (u32)(id & 7) * 1024 + (u32)lane * 16;
                u32 L = unswz(p);
                u32 row = L >> 6, colb = L & 63;
                const char* src;
                u32 loff;
                if (id < 8) {
                    src = (const char*)Wh + ((size_t)(n0 + row)) * 2048 + (size_t)koff * 2 + colb;
                    loff = OFF_BH + (p & 0xFFFFFC00u);
                } else if (TERMS == 3 && id < 16) {
                    src = (const char*)Wl + ((size_t)(n0 + row)) * 2048 + (size_t)koff * 2 + colb;
                    loff = OFF_BL + (p & 0xFFFFFC00u);
                } else {
                    src = (const char*)Xb + ((size_t)(m0 + row)) * 2048 + (size_t)koff * 2 + colb;
                    loff = OFF_AH + (p & 0xFFFFFC00u);
                }
                gl_lds16(src, smem + loff);
            }
        }
        if (XMODE == 0) {
            const int row = tid >> 1, half = tid & 1;
            const float* xr = Xf + ((size_t)(m0 + row)) * HID + koff + half * 16;
            float4 f0 = ((const float4*)xr)[0], f1 = ((const float4*)xr)[1],
                   f2 = ((const float4*)xr)[2], f3 = ((const float4*)xr)[3];
            float v[16] = {f0.x, f0.y, f0.z, f0.w, f1.x, f1.y, f1.z, f1.w,
                           f2.x, f2.y, f2.z, f2.w, f3.x, f3.y, f3.z, f3.w};
#pragma unroll
            for (int s = 0; s < 2; ++s) {
                us8 h, l8;
#pragma unroll
                for (int i = 0; i < 8; ++i) {
                    u16 hh = f2b(v[s * 8 + i]);
                    h[i] = hh;
                    if (TERMS == 3) l8[i] = f2b(v[s * 8 + i] - b2f(hh));
                }
                u32 ph = swz((u32)row * 64 + (u32)half * 32 + (u32)s * 16);
                *(us8*)(smem + OFF_AH + ph) = h;
                if (TERMS == 3) *(us8*)(smem + OFF_AL + ph) = l8;
            }
        }
        __syncthreads();
        bfrag ah[4], al[4];
#pragma unroll
        for (int mi = 0; mi < 4; ++mi) {
            ah[mi] = *(const bfrag*)(smem + OFF_AH + pa[mi]);
            if (TERMS == 3) al[mi] = *(const bfrag*)(smem + OFF_AL + pa[mi]);
        }
#pragma unroll
        for (int ni = 0; ni < 4; ++ni) {
            bfrag bh = *(const bfrag*)(smem + OFF_BH + pb[ni]);
            bfrag bl;
            if (TERMS == 3) bl = *(const bfrag*)(smem + OFF_BL + pb[ni]);
#pragma unroll
            for (int mi = 0; mi < 4; ++mi) {
                acc[mi][ni] = __builtin_amdgcn_mfma_f32_16x16x32_bf16(ah[mi], bh, acc[mi][ni], 0, 0, 0);
                if (TERMS == 3) {
                    acc[mi][ni] = __builtin_amdgcn_mfma_f32_16x16x32_bf16(ah[mi], bl, acc[mi][ni], 0, 0, 0);
                    acc[mi][ni] = __builtin_amdgcn_mfma_f32_16x16x32_bf16(al[mi], bh, acc[mi][ni], 0, 0, 0);
                }
            }
        }
        __syncthreads();
    }
#pragma unroll
    for (int mi = 0; mi < 4; ++mi) {
#pragma unroll
        for (int ni = 0; ni < 4; ++ni) {
            const u32 n = n0 + wc * 64 + ni * 16 + c;
            const u32 mb = m0 + wr * 64 + mi * 16 + 4 * g;
            if (EPI == 0) {
                float bv = bias[n];
#pragma unroll
                for (int r = 0; r < 4; ++r)
                    Of[(size_t)(mb + r) * HID + n] = acc[mi][ni][r] + bv;
            } else if (EPI == 2) {
                const u32 h = n >> 6, d = n & 63;
                const u32 b_ = mb >> 10, s = mb & 1023;
                size_t base = ((size_t)(b_ * NH + h) * SEQ + s) * 64 + d;
#pragma unroll
                for (int r = 0; r < 4; ++r) {
                    float v = acc[mi][ni][r] * scale;
                    u16 hh = f2b(v);
                    O1[base + (size_t)r * 64] = hh;
                    O2[base + (size_t)r * 64] = f2b(v - b2f(hh));
                }
            } else {   // EPI 3: V^T [b,h,d,s]
                const u32 h = n >> 6, d = n & 63;
                const u32 b_ = mb >> 10, s = mb & 1023;
                us4 o;
#pragma unroll
                for (int r = 0; r < 4; ++r) o[r] = f2b(acc[mi][ni][r]);
                *(us4*)&O1[((size_t)(b_ * NH + h) * 64 + d) * SEQ + s] = o;
            }
        }
    }
}

// ---------------------------------------------------------------------------
// Flash attention, swapped-QK^T MFMA (S^T = mfma(K,Q)) -> lane-local softmax.
// Block = (b, head, 64 Q rows), 4 waves (16 q each; lane c owns q=w*16+c).
// All staging via gl_lds (hoisted pointer increments). P^T packed in-reg
// (cvt_pk) -> per-wave LDS word buffer -> PV B-operand. Defer-max THR=8.
// ---------------------------------------------------------------------------
__global__ __launch_bounds__(256) void attn_mfma(
    const u16* __restrict__ Qh, const u16* __restrict__ Ql,
    const u16* __restrict__ Kh, const u16* __restrict__ Kl,
    const u16* __restrict__ Vt, u16* __restrict__ Cc)
{
    __shared__ __align__(16) u16 sQH[4096], sQL[4096], sKH[4096], sKL[4096], sVT[4096];
    __shared__ __align__(16) char sPw[8192];   // 4 waves x 2KB: P^T[q=c][k-word]

    u32 bid = blockIdx.x;
    u32 wg = (bid & 7) * 256 + (bid >> 3);   // 2048 blocks, XCD-chunked
    const int b = wg >> 8;
    const int head = (wg >> 4) & 15;
    const int q0 = (wg & 15) * 64;

    const int tid = threadIdx.x;
    const int w = tid >> 6, lane = tid & 63, c = lane & 15, g = lane >> 4;

    const size_t hb = (size_t)(b * NH + head);
    const char* gQH = (const char*)(Qh + (hb * SEQ + q0) * 64);
    const char* gQL = (const char*)(Ql + (hb * SEQ + q0) * 64);
    const char* gKH = (const char*)(Kh + hb * SEQ * 64);
    const char* gKL = (const char*)(Kl + hb * SEQ * 64);
    const char* gVT = (const char*)(Vt + hb * 64 * SEQ);

    // ---- stage Q tiles once (2 tiles x 8 segs over 4 waves) ----
    for (int t = w; t < 16; t += 4) {
        u32 seg = (u32)(t & 7);
        u32 ps = swz128(seg * 1024 + (u32)lane * 16);
        const char* src = ((t < 8) ? gQH : gQL) + ps;
        u16* dst = ((t < 8) ? sQH : sQL) + seg * 512;
        gl_lds16(src, dst);
    }

    // ---- hoisted K/VT staging pointers: wave loads segs {w, w+4} of each tile ----
    const u32 ps0 = swz128((u32)w * 1024 + (u32)lane * 16);
    const u32 ps1 = swz128((u32)(w + 4) * 1024 + (u32)lane * 16);
    const char* pKH0 = gKH + ps0;  const char* pKH1 = gKH + ps1;
    const char* pKL0 = gKL + ps0;  const char* pKL1 = gKL + ps1;
    const char* pVT0 = gVT + (size_t)(ps0 >> 7) * (SEQ * 2) + (ps0 & 127);
    const char* pVT1 = gVT + (size_t)(ps1 >> 7) * (SEQ * 2) + (ps1 & 127);
    u16* dKH0 = sKH + w * 512;        u16* dKH1 = sKH + (w + 4) * 512;
    u16* dKL0 = sKL + w * 512;        u16* dKL1 = sKL + (w + 4) * 512;
    u16* dVT0 = sVT + w * 512;        u16* dVT1 = sVT + (w + 4) * 512;

    // per-wave P buffer addressing (XOR bits 4-6 with c&7)
    char* pwBase = sPw + w * 2048;
    const u32 pwRow = (u32)c * 128;
    const u32 pwX = ((u32)(c & 7)) << 4;

    float m_ = -1e30f, l_ = 0.f;
    f32x4 acc[4];
#pragma unroll
    for (int j = 0; j < 4; ++j) acc[j] = f32x4{0.f, 0.f, 0.f, 0.f};
    bfrag qh[2], ql[2];

    for (int kc = 0; kc < SEQ / 64; ++kc) {
        __syncthreads();   // prior chunk's K/VT reads done
        gl_lds16(pKH0, dKH0); gl_lds16(pKH1, dKH1);
        gl_lds16(pKL0, dKL0); gl_lds16(pKL1, dKL1);
        gl_lds16(pVT0, dVT0); gl_lds16(pVT1, dVT1);
        pKH0 += 8192; pKH1 += 8192; pKL0 += 8192; pKL1 += 8192;
        pVT0 += 128;  pVT1 += 128;
        __syncthreads();   // staged data (incl Q on kc=0) visible

        if (kc == 0) {   // hoist Q fragments (B-operand: col=q=w*16+c, d-contig)
#pragma unroll
            for (int ks = 0; ks < 2; ++ks) {
                u32 aoff = swz128((u32)(w * 16 + c) * 128 + (u32)ks * 64 + (u32)g * 16);
                qh[ks] = *(const bfrag*)((const char*)sQH + aoff);
                ql[ks] = *(const bfrag*)((const char*)sQL + aoff);
            }
        }

        // ---- S^T = K Q^T: lane (c,g) gets q=w*16+c, k=jf*16+4g+r ----
        f32x4 s4[4];
#pragma unroll
        for (int j = 0; j < 4; ++j) s4[j] = f32x4{0.f, 0.f, 0.f, 0.f};
#pragma unroll
        for (int ks = 0; ks < 2; ++ks) {
#pragma unroll
            for (int jf = 0; jf < 4; ++jf) {
                u32 koff = swz128((u32)(jf * 16 + c) * 128 + (u32)ks * 64 + (u32)g * 16);
                bfrag kh_ = *(const bfrag*)((const char*)sKH + koff);
                bfrag kl_ = *(const bfrag*)((const char*)sKL + koff);
                s4[jf] = __builtin_amdgcn_mfma_f32_16x16x32_bf16(kh_, qh[ks], s4[jf], 0, 0, 0);
                s4[jf] = __builtin_amdgcn_mfma_f32_16x16x32_bf16(kl_, qh[ks], s4[jf], 0, 0, 0);
                s4[jf] = __builtin_amdgcn_mfma_f32_16x16x32_bf16(kh_, ql[ks], s4[jf], 0, 0, 0);
            }
        }

        // ---- lane-local softmax (16 scores; cross-g reduce via 2 shuffles) ----
        float pmax = s4[0][0];
#pragma unroll
        for (int jf = 0; jf < 4; ++jf)
#pragma unroll
            for (int r = 0; r < 4; ++r) pmax = fmaxf(pmax, s4[jf][r]);
        pmax = fmaxf(pmax, __shfl_xor(pmax, 16));
        pmax = fmaxf(pmax, __shfl_xor(pmax, 32));

        if (!__all(pmax <= m_ + 8.f)) {          // defer-max (THR=8, base-2)
            float mn = fmaxf(m_, pmax);
            float scl = exp2f(m_ - mn);
            m_ = mn;
            l_ *= scl;
#pragma unroll
            for (int jd = 0; jd < 4; ++jd) {
                f32x4 t = acc[jd];
                t[0] *= scl; t[1] *= scl; t[2] *= scl; t[3] *= scl;
                acc[jd] = t;
            }
        }

        float p[16];
        float rs = 0.f;
#pragma unroll
        for (int jf = 0; jf < 4; ++jf)
#pragma unroll
            for (int r = 0; r < 4; ++r) {
                float pv = exp2f(s4[jf][r] - m_);
                p[jf * 4 + r] = pv;
                rs += pv;
            }
        rs += __shfl_xor(rs, 16);
        rs += __shfl_xor(rs, 32);
        l_ += rs;

        // ---- pack P^T and write per-wave word buffer (word kw=8jf+2g+t) ----
#pragma unroll
        for (int jf = 0; jf < 4; ++jf) {
            u32 w0 = packbf(p[jf * 4 + 0], p[jf * 4 + 1]);
            u32 w1 = packbf(p[jf * 4 + 2], p[jf * 4 + 3]);
            u32 off = (pwRow + (u32)(32 * jf + 8 * g)) ^ pwX;
            *(u32x2*)(pwBase + off) = u32x2{w0, w1};
        }

        // ---- O^T += V^T P^T: acc[jd] lane (c,g): q=w*16+c, d=jd*16+4g+r ----
#pragma unroll
        for (int ks = 0; ks < 2; ++ks) {
            u32 roff = (pwRow + (u32)(64 * ks + 16 * g)) ^ pwX;
            bfrag pf = *(const bfrag*)(pwBase + roff);
#pragma unroll
            for (int jd = 0; jd < 4; ++jd) {
                u32 voff = swz128((u32)(jd * 16 + c) * 128 + (u32)ks * 64 + (u32)g * 16);
                bfrag vv = *(const bfrag*)((const char*)sVT + voff);
                acc[jd] = __builtin_amdgcn_mfma_f32_16x16x32_bf16(vv, pf, acc[jd], 0, 0, 0);
            }
        }
    }

    // ---- normalize + write concat (bf16, [b, s, h*64+d]); us4 stores ----
    float inv = 1.f / l_;
    size_t rowb = ((size_t)(b * SEQ + q0 + w * 16 + c)) * HID + head * DH;
#pragma unroll
    for (int jd = 0; jd < 4; ++jd) {
        us4 o;
#pragma unroll
        for (int r = 0; r < 4; ++r) o[r] = f2b(acc[jd][r] * inv);
        *(us4*)&Cc[rowb + jd * 16 + 4 * g] = o;
    }
}

// ---------------------------------------------------------------------------
extern "C" void kernel_launch(void* const* d_in, const int* in_sizes, int n_in,
                              void* d_out, int out_size, void* d_ws, size_t ws_size,
                              hipStream_t stream)
{
    const float* dec = (const float*)d_in[0];
    const float* enc = (const float*)d_in[1];
    const float* Wq = (const float*)d_in[2];
    const float* Wk = (const float*)d_in[3];
    const float* Wv = (const float*)d_in[4];
    const float* Wo = (const float*)d_in[5];
    const float* bo = (const float*)d_in[6];
    float* out = (float*)d_out;

    char* ws = (char*)d_ws;
    const size_t MB = 1u << 20;
    u16* Eh  = (u16*)ws;                       // 16 MiB   (aliased by Cc later)
    u16* Qhg = (u16*)(ws + 16 * MB);           // 16 MiB
    u16* Qlg = (u16*)(ws + 32 * MB);           // 16 MiB
    u16* Khg = (u16*)(ws + 48 * MB);           // 16 MiB
    u16* Klg = (u16*)(ws + 64 * MB);           // 16 MiB
    u16* Vtg = (u16*)(ws + 80 * MB);           // 16 MiB
    u16* Wqh = (u16*)(ws + 96 * MB);           // 6 x 2 MiB weights
    u16* Wql = Wqh + (1u << 20);
    u16* Wkh = Wql + (1u << 20);
    u16* Wkl = Wkh + (1u << 20);
    u16* Wvh = Wkl + (1u << 20);
    u16* Woh = Wvh + (1u << 20);               // total 108 MiB
    u16* Cc  = Eh;                             // Eh dead after V-GEMM

    prep<<<2048, 256, 0, stream>>>(enc, Wq, Wk, Wv, Wo,
                                   Eh, Wqh, Wql, Wkh, Wkl, Wvh, Woh);

    // Q: scale folded (0.125*log2e), split hi/lo, head-major
    gemm_mfma<3, 0, 2><<<512, 256, 0, stream>>>(dec, nullptr, Wqh, Wql, nullptr,
                                                SCALE_Q, nullptr, Qhg, Qlg);
    // K: split hi/lo, head-major
    gemm_mfma<3, 0, 2><<<512, 256, 0, stream>>>(enc, nullptr, Wkh, Wkl, nullptr,
                                                1.0f, nullptr, Khg, Klg);
    // V: bf16 A via gl_lds, V^T output
    gemm_mfma<1, 1, 3><<<512, 256, 0, stream>>>(nullptr, Eh, Wvh, nullptr, nullptr,
                                                1.0f, nullptr, Vtg, nullptr);

    attn_mfma<<<2048, 256, 0, stream>>>(Qhg, Qlg, Khg, Klg, Vtg, Cc);

    // O: bf16 A via gl_lds, f32 + bias
    gemm_mfma<1, 1, 0><<<512, 256, 0, stream>>>(nullptr, Cc, Woh, nullptr, bo,
                                                1.0f, out, nullptr, nullptr);
}

// Round 8
// 417.112 us; speedup vs baseline: 3.8103x; 1.0006x over previous
//
#include <hip/hip_runtime.h>
#include <hip/hip_bf16.h>
#include <math.h>

#define HID 1024
#define NH 16
#define DH 64
#define BATCH 8
#define SEQ 1024
#define MTOT (BATCH * SEQ) /* 8192 */

typedef __attribute__((ext_vector_type(8))) short bfrag;   // 8 bf16 MFMA operand
typedef __attribute__((ext_vector_type(4))) float f32x4;   // MFMA accumulator
typedef __attribute__((ext_vector_type(8))) unsigned short us8;
typedef __attribute__((ext_vector_type(4))) unsigned short us4;
typedef __attribute__((ext_vector_type(2))) unsigned int u32x2;
typedef unsigned int u32;
typedef unsigned short u16;

#define SCALE_Q 0.18033688011112042f   /* 0.125 * log2(e): exp2-domain softmax */

__device__ __forceinline__ u16 f2b(float f) {              // f32 -> bf16 RNE
    u32 u = __float_as_uint(f);
    return (u16)((u + 0x7FFFu + ((u >> 16) & 1u)) >> 16);
}
__device__ __forceinline__ float b2f(u16 h) { return __uint_as_float(((u32)h) << 16); }

__device__ __forceinline__ u32 packbf(float a, float b) {  // 2xf32 -> packed bf16 (cvt_pk)
    __hip_bfloat162 t = __float22bfloat162_rn(float2{a, b});
    u32 r;
    __builtin_memcpy(&r, &t, 4);
    return r;
}

__device__ __forceinline__ float exp2_hw(float x) {        // v_exp_f32: D = 2^S0
    float r;
    asm("v_exp_f32 %0, %1" : "=v"(r) : "v"(x));
    return r;
}

__device__ __forceinline__ void gl_lds16(const void* g, void* l) {
    __builtin_amdgcn_global_load_lds(
        (const __attribute__((address_space(1))) unsigned int*)g,
        (__attribute__((address_space(3))) unsigned int*)l, 16, 0, 0);
}

// --- GEMM tile swizzle (64B logical rows), proven in R1 ---
__device__ __forceinline__ u32 swz(u32 L) { return L ^ (((L >> 6) & 7u) << 4); }
__device__ __forceinline__ u32 unswz(u32 p) {
    u32 b = ((((p >> 6) ^ (p >> 8)) & 1u) << 4) | (((p >> 7) & 1u) << 5) | (((p >> 8) & 1u) << 6);
    return p ^ b;
}
// --- attn tile swizzle (128B rows): bits 7-9 -> 4-6, disjoint => involution ---
__device__ __forceinline__ u32 swz128(u32 L) { return L ^ (((L >> 7) & 7u) << 4); }

// ---------------------------------------------------------------------------
// prep: enc -> Eh (bf16); Wq,Wk -> hi/lo split; Wv,Wo -> bf16. One launch.
// ---------------------------------------------------------------------------
__global__ __launch_bounds__(256) void prep(
    const float* __restrict__ enc,
    const float* __restrict__ Wq, const float* __restrict__ Wk,
    const float* __restrict__ Wv, const float* __restrict__ Wo,
    u16* __restrict__ Eh,
    u16* __restrict__ Wqh, u16* __restrict__ Wql,
    u16* __restrict__ Wkh, u16* __restrict__ Wkl,
    u16* __restrict__ Wvh, u16* __restrict__ Woh)
{
    const int NX4 = MTOT * HID / 4;   // 2,097,152
    const int NW4 = HID * HID / 4;    // 262,144
    const int total = NX4 + 4 * NW4;
    for (int i = blockIdx.x * blockDim.x + threadIdx.x; i < total;
         i += gridDim.x * blockDim.x) {
        if (i < NX4) {
            float4 f = ((const float4*)enc)[i];
            us4 h;
            h[0] = f2b(f.x); h[1] = f2b(f.y); h[2] = f2b(f.z); h[3] = f2b(f.w);
            ((us4*)Eh)[i] = h;
        } else {
            int j = i - NX4;
            int rgn = j / NW4, k = j - rgn * NW4;
            const float* src = (rgn == 0) ? Wq : (rgn == 1) ? Wk : (rgn == 2) ? Wv : Wo;
            float4 f = ((const float4*)src)[k];
            float v[4] = {f.x, f.y, f.z, f.w};
            us4 h, l;
#pragma unroll
            for (int q = 0; q < 4; ++q) {
                u16 hh = f2b(v[q]);
                h[q] = hh;
                l[q] = f2b(v[q] - b2f(hh));
            }
            if (rgn == 0) { ((us4*)Wqh)[k] = h; ((us4*)Wql)[k] = l; }
            else if (rgn == 1) { ((us4*)Wkh)[k] = h; ((us4*)Wkl)[k] = l; }
            else if (rgn == 2) { ((us4*)Wvh)[k] = h; }
            else { ((us4*)Woh)[k] = h; }
        }
    }
}

// ---------------------------------------------------------------------------
// GEMM  Y[M,N] = X[M,K] @ W[N,K]^T.  (unchanged from R4/R5 — verified)
// ---------------------------------------------------------------------------
template <int TERMS, int XMODE, int EPI>
__global__ __launch_bounds__(256) void gemm_mfma(
    const float* __restrict__ Xf, const u16* __restrict__ Xb,
    const u16* __restrict__ Wh, const u16* __restrict__ Wl,
    const float* __restrict__ bias, float scale,
    float* __restrict__ Of, u16* __restrict__ O1, u16* __restrict__ O2)
{
    constexpr u32 OFF_AH = 0, OFF_BH = 8192, OFF_AL = 16384, OFF_BL = 24576;
    __shared__ __align__(16) char smem[(TERMS == 3) ? 32768 : 16384];

    u32 bid = blockIdx.x;
    u32 wg = (bid & 7) * 64 + (bid >> 3);     // 512 blocks, XCD-chunked
    const u32 m0 = (wg >> 3) * 128, n0 = (wg & 7) * 128;

    const int tid = threadIdx.x;
    const int w = tid >> 6, lane = tid & 63, c = lane & 15, g = lane >> 4;
    const int wr = w >> 1, wc = w & 1;

    u32 pa[4], pb[4];
#pragma unroll
    for (int i = 0; i < 4; ++i) {
        pa[i] = swz((u32)(wr * 64 + i * 16 + c) * 64 + (u32)g * 16);
        pb[i] = swz((u32)(wc * 64 + i * 16 + c) * 64 + (u32)g * 16);
    }

    f32x4 acc[4][4];
#pragma unroll
    for (int i = 0; i < 4; ++i)
#pragma unroll
        for (int j = 0; j < 4; ++j) acc[i][j] = f32x4{0.f, 0.f, 0.f, 0.f};

    for (int kb = 0; kb < HID / 32; ++kb) {
        const int koff = kb * 32;
        {
            const int nB = (TERMS == 3) ? 16 : 8;
            const int total = nB + ((XMODE == 1) ? 8 : 0);
            for (int id = w; id < total; id += 4) {
                u32 p = (u32)(id & 7) * 1024 + (u32)lane * 16;
                u32 L = unswz(p);
                u32 row = L >> 6, colb = L & 63;
                const char* src;
                u32 loff;
                if (id < 8) {
                    src = (const char*)Wh + ((size_t)(n0 + row)) * 2048 + (size_t)koff * 2 + colb;
                    loff = OFF_BH + (p & 0xFFFFFC00u);
                } else if (TERMS == 3 && id < 16) {
                    src = (const char*)Wl + ((size_t)(n0 + row)) * 2048 + (size_t)koff * 2 + colb;
                    loff = OFF_BL + (p & 0xFFFFFC00u);
                } else {
                    src = (const char*)Xb + ((size_t)(m0 + row)) * 2048 + (size_t)koff * 2 + colb;
                    loff = OFF_AH + (p & 0xFFFFFC00u);
                }
                gl_lds16(src, smem + loff);
            }
        }
        if (XMODE == 0) {
            const int row = tid >> 1, half = tid & 1;
            const float* xr = Xf + ((size_t)(m0 + row)) * HID + koff + half * 16;
            float4 f0 = ((const float4*)xr)[0], f1 = ((const float4*)xr)[1],
                   f2 = ((const float4*)xr)[2], f3 = ((const float4*)xr)[3];
            float v[16] = {f0.x, f0.y, f0.z, f0.w, f1.x, f1.y, f1.z, f1.w,
                           f2.x, f2.y, f2.z, f2.w, f3.x, f3.y, f3.z, f3.w};
#pragma unroll
            for (int s = 0; s < 2; ++s) {
                us8 h, l8;
#pragma unroll
                for (int i = 0; i < 8; ++i) {
                    u16 hh = f2b(v[s * 8 + i]);
                    h[i] = hh;
                    if (TERMS == 3) l8[i] = f2b(v[s * 8 + i] - b2f(hh));
                }
                u32 ph = swz((u32)row * 64 + (u32)half * 32 + (u32)s * 16);
                *(us8*)(smem + OFF_AH + ph) = h;
                if (TERMS == 3) *(us8*)(smem + OFF_AL + ph) = l8;
            }
        }
        __syncthreads();
        bfrag ah[4], al[4];
#pragma unroll
        for (int mi = 0; mi < 4; ++mi) {
            ah[mi] = *(const bfrag*)(smem + OFF_AH + pa[mi]);
            if (TERMS == 3) al[mi] = *(const bfrag*)(smem + OFF_AL + pa[mi]);
        }
#pragma unroll
        for (int ni = 0; ni < 4; ++ni) {
            bfrag bh = *(const bfrag*)(smem + OFF_BH + pb[ni]);
            bfrag bl;
            if (TERMS == 3) bl = *(const bfrag*)(smem + OFF_BL + pb[ni]);
#pragma unroll
            for (int mi = 0; mi < 4; ++mi) {
                acc[mi][ni] = __builtin_amdgcn_mfma_f32_16x16x32_bf16(ah[mi], bh, acc[mi][ni], 0, 0, 0);
                if (TERMS == 3) {
                    acc[mi][ni] = __builtin_amdgcn_mfma_f32_16x16x32_bf16(ah[mi], bl, acc[mi][ni], 0, 0, 0);
                    acc[mi][ni] = __builtin_amdgcn_mfma_f32_16x16x32_bf16(al[mi], bh, acc[mi][ni], 0, 0, 0);
                }
            }
        }
        __syncthreads();
    }
#pragma unroll
    for (int mi = 0; mi < 4; ++mi) {
#pragma unroll
        for (int ni = 0; ni < 4; ++ni) {
            const u32 n = n0 + wc * 64 + ni * 16 + c;
            const u32 mb = m0 + wr * 64 + mi * 16 + 4 * g;
            if (EPI == 0) {
                float bv = bias[n];
#pragma unroll
                for (int r = 0; r < 4; ++r)
                    Of[(size_t)(mb + r) * HID + n] = acc[mi][ni][r] + bv;
            } else if (EPI == 2) {
                const u32 h = n >> 6, d = n & 63;
                const u32 b_ = mb >> 10, s = mb & 1023;
                size_t base = ((size_t)(b_ * NH + h) * SEQ + s) * 64 + d;
#pragma unroll
                for (int r = 0; r < 4; ++r) {
                    float v = acc[mi][ni][r] * scale;
                    u16 hh = f2b(v);
                    O1[base + (size_t)r * 64] = hh;
                    O2[base + (size_t)r * 64] = f2b(v - b2f(hh));
                }
            } else {   // EPI 3: V^T [b,h,d,s]
                const u32 h = n >> 6, d = n & 63;
                const u32 b_ = mb >> 10, s = mb & 1023;
                us4 o;
#pragma unroll
                for (int r = 0; r < 4; ++r) o[r] = f2b(acc[mi][ni][r]);
                *(us4*)&O1[((size_t)(b_ * NH + h) * 64 + d) * SEQ + s] = o;
            }
        }
    }
}

// ---------------------------------------------------------------------------
// Flash attention, swapped-QK^T MFMA, 2-phase stage-ahead double-buffer.
// Block = (b, head, 64 Q rows), 4 waves (lane c owns q=w*16+c).
// Buffers: sBuf[2][KH 8K | KL 8K | VT 8K]; Q staged into sBuf[1] then
// hoisted to regs (region reused as the 2nd buffer). One barrier/chunk.
// ---------------------------------------------------------------------------
__global__ __launch_bounds__(256) void attn_mfma(
    const u16* __restrict__ Qh, const u16* __restrict__ Ql,
    const u16* __restrict__ Kh, const u16* __restrict__ Kl,
    const u16* __restrict__ Vt, u16* __restrict__ Cc)
{
    __shared__ __align__(16) char sBuf[2][24576];   // [buf][KH|KL|VT]
    __shared__ __align__(16) char sPw[8192];        // 4 waves x 2KB: P^T[q=c][k-word]

    u32 bid = blockIdx.x;
    u32 wg = (bid & 7) * 256 + (bid >> 3);   // 2048 blocks, XCD-chunked
    const int b = wg >> 8;
    const int head = (wg >> 4) & 15;
    const int q0 = (wg & 15) * 64;

    const int tid = threadIdx.x;
    const int w = tid >> 6, lane = tid & 63, c = lane & 15, g = lane >> 4;

    const size_t hb = (size_t)(b * NH + head);
    const char* gQH = (const char*)(Qh + (hb * SEQ + q0) * 64);
    const char* gQL = (const char*)(Ql + (hb * SEQ + q0) * 64);
    const char* gKH = (const char*)(Kh + hb * SEQ * 64);
    const char* gKL = (const char*)(Kl + hb * SEQ * 64);
    const char* gVT = (const char*)(Vt + hb * 64 * SEQ);

    char* b0 = sBuf[0];
    char* b1 = sBuf[1];

    // ---- hoisted staging state: wave loads segs {w, w+4} of each 8KB tile ----
    const u32 ps0 = swz128((u32)w * 1024 + (u32)lane * 16);
    const u32 ps1 = swz128((u32)(w + 4) * 1024 + (u32)lane * 16);
    const char* pKH0 = gKH + ps0;  const char* pKH1 = gKH + ps1;
    const char* pKL0 = gKL + ps0;  const char* pKL1 = gKL + ps1;
    const char* pVT0 = gVT + (size_t)(ps0 >> 7) * (SEQ * 2) + (ps0 & 127);
    const char* pVT1 = gVT + (size_t)(ps1 >> 7) * (SEQ * 2) + (ps1 & 127);
    const u32 d0 = (u32)w * 1024, d1 = (u32)(w + 4) * 1024;

    auto STAGE = [&](char* bb) {
        gl_lds16(pKH0, bb + d0);          gl_lds16(pKH1, bb + d1);
        gl_lds16(pKL0, bb + 8192 + d0);   gl_lds16(pKL1, bb + 8192 + d1);
        gl_lds16(pVT0, bb + 16384 + d0);  gl_lds16(pVT1, bb + 16384 + d1);
        pKH0 += 8192; pKH1 += 8192; pKL0 += 8192; pKL1 += 8192;
        pVT0 += 128;  pVT1 += 128;
    };

    // ---- prologue: Q -> b1 (hi at +0, lo at +8192), chunk0 -> b0 ----
    for (int t = w; t < 16; t += 4) {
        u32 seg = (u32)(t & 7);
        u32 ps = swz128(seg * 1024 + (u32)lane * 16);
        const char* src = ((t < 8) ? gQH : gQL) + ps;
        gl_lds16(src, b1 + ((t < 8) ? 0u : 8192u) + seg * 1024);
    }
    STAGE(b0);
    __syncthreads();

    // ---- hoist Q fragments, then release b1 for staging ----
    bfrag qh[2], ql[2];
#pragma unroll
    for (int ks = 0; ks < 2; ++ks) {
        u32 aoff = swz128((u32)(w * 16 + c) * 128 + (u32)ks * 64 + (u32)g * 16);
        qh[ks] = *(const bfrag*)(b1 + aoff);
        ql[ks] = *(const bfrag*)(b1 + 8192 + aoff);
    }
    __syncthreads();

    // ---- loop-invariant LDS read offsets ----
    u32 koff[2][4];   // also serves VT (identical formula)
#pragma unroll
    for (int ks = 0; ks < 2; ++ks)
#pragma unroll
        for (int jf = 0; jf < 4; ++jf)
            koff[ks][jf] = swz128((u32)(jf * 16 + c) * 128 + (u32)ks * 64 + (u32)g * 16);

    char* pwBase = sPw + w * 2048;
    const u32 pwRow = (u32)c * 128;
    const u32 pwX = ((u32)(c & 7)) << 4;

    float m_ = -1e30f, l_ = 0.f;
    f32x4 acc[4];
#pragma unroll
    for (int j = 0; j < 4; ++j) acc[j] = f32x4{0.f, 0.f, 0.f, 0.f};

    auto COMPUTE = [&](const char* bb) {
        // ---- S^T = K Q^T: lane (c,g): q=w*16+c, k=16jf+4g+r ----
        f32x4 s4[4];
#pragma unroll
        for (int j = 0; j < 4; ++j) s4[j] = f32x4{0.f, 0.f, 0.f, 0.f};
        __builtin_amdgcn_s_setprio(1);
#pragma unroll
        for (int ks = 0; ks < 2; ++ks) {
#pragma unroll
            for (int jf = 0; jf < 4; ++jf) {
                bfrag kh_ = *(const bfrag*)(bb + koff[ks][jf]);
                bfrag kl_ = *(const bfrag*)(bb + 8192 + koff[ks][jf]);
                s4[jf] = __builtin_amdgcn_mfma_f32_16x16x32_bf16(kh_, qh[ks], s4[jf], 0, 0, 0);
                s4[jf] = __builtin_amdgcn_mfma_f32_16x16x32_bf16(kl_, qh[ks], s4[jf], 0, 0, 0);
                s4[jf] = __builtin_amdgcn_mfma_f32_16x16x32_bf16(kh_, ql[ks], s4[jf], 0, 0, 0);
            }
        }
        __builtin_amdgcn_s_setprio(0);

        // ---- lane-local softmax (16 scores; cross-g via 2 shuffles) ----
        float pmax = s4[0][0];
#pragma unroll
        for (int jf = 0; jf < 4; ++jf)
#pragma unroll
            for (int r = 0; r < 4; ++r) pmax = fmaxf(pmax, s4[jf][r]);
        pmax = fmaxf(pmax, __shfl_xor(pmax, 16));
        pmax = fmaxf(pmax, __shfl_xor(pmax, 32));

        if (!__all(pmax <= m_ + 8.f)) {          // defer-max (THR=8, base-2)
            float mn = fmaxf(m_, pmax);
            float scl = exp2_hw(m_ - mn);
            m_ = mn;
            l_ *= scl;
#pragma unroll
            for (int jd = 0; jd < 4; ++jd) {
                f32x4 t = acc[jd];
                t[0] *= scl; t[1] *= scl; t[2] *= scl; t[3] *= scl;
                acc[jd] = t;
            }
        }

        float p[16];
        float rs = 0.f;
#pragma unroll
        for (int jf = 0; jf < 4; ++jf)
#pragma unroll
            for (int r = 0; r < 4; ++r) {
                float pv = exp2_hw(s4[jf][r] - m_);
                p[jf * 4 + r] = pv;
                rs += pv;
            }
        rs += __shfl_xor(rs, 16);
        rs += __shfl_xor(rs, 32);
        l_ += rs;

        // ---- pack P^T -> per-wave word buffer (wave-private, no barrier) ----
#pragma unroll
        for (int jf = 0; jf < 4; ++jf) {
            u32 w0 = packbf(p[jf * 4 + 0], p[jf * 4 + 1]);
            u32 w1 = packbf(p[jf * 4 + 2], p[jf * 4 + 3]);
            u32 off = (pwRow + (u32)(32 * jf + 8 * g)) ^ pwX;
            *(u32x2*)(pwBase + off) = u32x2{w0, w1};
        }

        // ---- O^T += V^T P^T ----
#pragma unroll
        for (int ks = 0; ks < 2; ++ks) {
            u32 roff = (pwRow + (u32)(64 * ks + 16 * g)) ^ pwX;
            bfrag pf = *(const bfrag*)(pwBase + roff);
            __builtin_amdgcn_s_setprio(1);
#pragma unroll
            for (int jd = 0; jd < 4; ++jd) {
                bfrag vv = *(const bfrag*)(bb + 16384 + koff[ks][jd]);
                acc[jd] = __builtin_amdgcn_mfma_f32_16x16x32_bf16(vv, pf, acc[jd], 0, 0, 0);
            }
            __builtin_amdgcn_s_setprio(0);
        }
    };

    // ---- main loop: 16 chunks, 2x unrolled (static buffer addressing) ----
    for (int it = 0; it < 8; ++it) {
        STAGE(b1);          // chunk 2it+1 in flight (overwrites Q region on it=0)
        COMPUTE(b0);        // chunk 2it
        __syncthreads();    // b1 staged + b0 reads done
        if (it < 7) STAGE(b0);   // chunk 2it+2 in flight
        COMPUTE(b1);        // chunk 2it+1
        if (it < 7) __syncthreads();
    }

    // ---- normalize + write concat (bf16, [b, s, h*64+d]); us4 stores ----
    float inv = 1.f / l_;
    size_t rowb = ((size_t)(b * SEQ + q0 + w * 16 + c)) * HID + head * DH;
#pragma unroll
    for (int jd = 0; jd < 4; ++jd) {
        us4 o;
#pragma unroll
        for (int r = 0; r < 4; ++r) o[r] = f2b(acc[jd][r] * inv);
        *(us4*)&Cc[rowb + jd * 16 + 4 * g] = o;
    }
}

// ---------------------------------------------------------------------------
extern "C" void kernel_launch(void* const* d_in, const int* in_sizes, int n_in,
                              void* d_out, int out_size, void* d_ws, size_t ws_size,
                              hipStream_t stream)
{
    const float* dec = (const float*)d_in[0];
    const float* enc = (const float*)d_in[1];
    const float* Wq = (const float*)d_in[2];
    const float* Wk = (const float*)d_in[3];
    const float* Wv = (const float*)d_in[4];
    const float* Wo = (const float*)d_in[5];
    const float* bo = (const float*)d_in[6];
    float* out = (float*)d_out;

    char* ws = (char*)d_ws;
    const size_t MB = 1u << 20;
    u16* Eh  = (u16*)ws;                       // 16 MiB   (aliased by Cc later)
    u16* Qhg = (u16*)(ws + 16 * MB);           // 16 MiB
    u16* Qlg = (u16*)(ws + 32 * MB);           // 16 MiB
    u16* Khg = (u16*)(ws + 48 * MB);           // 16 MiB
    u16* Klg = (u16*)(ws + 64 * MB);           // 16 MiB
    u16* Vtg = (u16*)(ws + 80 * MB);           // 16 MiB
    u16* Wqh = (u16*)(ws + 96 * MB);           // 6 x 2 MiB weights
    u16* Wql = Wqh + (1u << 20);
    u16* Wkh = Wql + (1u << 20);
    u16* Wkl = Wkh + (1u << 20);
    u16* Wvh = Wkl + (1u << 20);
    u16* Woh = Wvh + (1u << 20);               // total 108 MiB
    u16* Cc  = Eh;                             // Eh dead after V-GEMM

    prep<<<2048, 256, 0, stream>>>(enc, Wq, Wk, Wv, Wo,
                                   Eh, Wqh, Wql, Wkh, Wkl, Wvh, Woh);

    // Q: scale folded (0.125*log2e), split hi/lo, head-major
    gemm_mfma<3, 0, 2><<<512, 256, 0, stream>>>(dec, nullptr, Wqh, Wql, nullptr,
                                                SCALE_Q, nullptr, Qhg, Qlg);
    // K: split hi/lo, head-major
    gemm_mfma<3, 0, 2><<<512, 256, 0, stream>>>(enc, nullptr, Wkh, Wkl, nullptr,
                                                1.0f, nullptr, Khg, Klg);
    // V: bf16 A via gl_lds, V^T output
    gemm_mfma<1, 1, 3><<<512, 256, 0, stream>>>(nullptr, Eh, Wvh, nullptr, nullptr,
                                                1.0f, nullptr, Vtg, nullptr);

    attn_mfma<<<2048, 256, 0, stream>>>(Qhg, Qlg, Khg, Klg, Vtg, Cc);

    // O: bf16 A via gl_lds, f32 + bias
    gemm_mfma<1, 1, 0><<<512, 256, 0, stream>>>(nullptr, Cc, Woh, nullptr, bo,
                                                1.0f, out, nullptr, nullptr);
}